// Round 5
// baseline (150.703 us; speedup 1.0000x reference)
//
#include <hip/hip_runtime.h>
#include <hip/hip_bf16.h>
#include <math.h>

// Problem dims (fixed by reference)
#define B_ROWS 8192
#define D_IN   256
#define H1_DIM 512
#define H2_DIM 256
#define D_OUT  64
#define EPSF   1e-12f
#define THRESH 0.9f
// hh-only gram screen: |fid_hh - fid_true| < 0.008 for unit vectors
// -> decisions outside (0.89, 0.91) are certain; band hits get exact refine.
#define BAND_LO 0.89f
#define BAND_HI 0.91f

typedef __attribute__((ext_vector_type(8))) short short8;   // 8 bf16 = 4 VGPR
typedef __attribute__((ext_vector_type(4))) float f32x4;

// fast tanh via hardware exp: tanh(|x|) = (1-e^{-2|x|})/(1+e^{-2|x|}), ~1e-7 rel err
__device__ inline float tanh_fast(float xx) {
  const float ax = fabsf(xx);
  const float t = __expf(-2.0f * ax);
  const float r = (1.0f - t) / (1.0f + t);
  return xx < 0.0f ? -r : r;
}

// split fp32x8 -> bf16 hi + bf16 mid (residual), fragment-packed
__device__ inline void splitf8(float4 a, float4 b, short8& h, short8& m) {
  float v[8] = {a.x, a.y, a.z, a.w, b.x, b.y, b.z, b.w};
  short h8[8], m8[8];
#pragma unroll
  for (int e = 0; e < 8; ++e) {
    __hip_bfloat16 hb = __float2bfloat16(v[e]);
    float hf = __bfloat162float(hb);
    __hip_bfloat16 mb = __float2bfloat16(v[e] - hf);
    h8[e] = *(short*)&hb;
    m8[e] = *(short*)&mb;
  }
  h = *(short8*)h8;
  m = *(short8*)m8;
}

// read 8 logical-consecutive floats at (row, kl) from an XOR-swizzled LDS buf.
// swizzle: dword index ^= (row&7)<<2 (16B-slot spread -> conflict-free b128)
__device__ inline void rd8_swz(const float* buf, int S, int row, int kl,
                               float4& a, float4& b) {
  const int xr = (row & 7) << 2;
  a = *(const float4*)&buf[(row * S + kl) ^ xr];
  b = *(const float4*)&buf[(row * S + kl + 4) ^ xr];
}

// ---------------- weight pre-pack (fragment-major bf16 hi/mid) ----------------
__device__ inline void pack8(const float* __restrict__ src, short* __restrict__ dh,
                             short* __restrict__ dm, int t, int C, int lgq) {
  const int lane = t & 63;
  const int g = t >> 6;
  const int q = g & ((1 << lgq) - 1);
  const int I = g >> lgq;
  const int row = I * 16 + (lane & 15);
  const int k0 = q * 32 + ((lane >> 4) << 3);
  const float* p = src + (size_t)row * C + k0;
  short8 hh, mm;
  splitf8(*(const float4*)p, *(const float4*)(p + 4), hh, mm);
  *(short8*)(dh + (size_t)t * 8) = hh;
  *(short8*)(dm + (size_t)t * 8) = mm;
}

__global__ __launch_bounds__(256)
void wpack(const float* __restrict__ W1, const float* __restrict__ W2,
           const float* __restrict__ W3,
           short* w1h, short* w1m, short* w2h, short* w2m,
           short* w3h, short* w3m) {
  const int b = blockIdx.x, tid = threadIdx.x;
  if (b < 64)        pack8(W1, w1h, w1m, b * 256 + tid, 256, 3);
  else if (b < 128)  pack8(W2, w2h, w2m, (b - 64) * 256 + tid, 512, 4);
  else               pack8(W3, w3h, w3m, (b - 128) * 256 + tid, 256, 3);
}

// ---------------- fully fused MLP, 16-row blocks (round-3 version) ----------------
// 512 blocks x 16 rows, 8 waves (512 thr). LDS 48KB -> 2 blocks/CU.
// (round-4's 32-row variant regressed: 1 block/CU killed latency hiding)
__global__ __launch_bounds__(512, 4)
void fused_mlp16(const float* __restrict__ x,
                 const short* __restrict__ w1h, const short* __restrict__ w1m,
                 const float* __restrict__ b1,
                 const short* __restrict__ w2h, const short* __restrict__ w2m,
                 const float* __restrict__ b2,
                 const short* __restrict__ w3h, const short* __restrict__ w3m,
                 const float* __restrict__ b3,
                 float* __restrict__ out, short* __restrict__ vph,
                 short* __restrict__ vpm) {
  __shared__ __align__(16) char smem[49152];
  short* xph   = (short*)smem;                // 8KB
  short* xpm   = (short*)(smem + 8192);       // 8KB
  float* wbuf1 = (float*)smem;                // 16KB
  float* wbuf3 = (float*)smem;                // 4KB
  short* h1h   = (short*)(smem + 16384);      // 16KB
  short* h1m   = (short*)(smem + 32768);      // 16KB
  float* wbuf2 = (float*)(smem + 16384);      // 16KB
  short* h2ph  = (short*)(smem + 32768);      // 8KB
  short* h2pm  = (short*)(smem + 40960);      // 8KB
  __shared__ float nsum[16];
  __shared__ float invn[16];

  const int tid = threadIdx.x;
  const int wave = tid >> 6, lane = tid & 63;
  const int r0 = blockIdx.x * 16;
  const int col16 = lane & 15;
  const int rbase = (lane >> 4) << 2;   // C-layout row base

  // ---- pack x block (16x256 fp32 -> frag hi/mid): 512 units, 1/thread ----
  {
    const int lu = tid & 63, q = tid >> 6;
    const float* p = x + (size_t)(r0 + (lu & 15)) * D_IN + q * 32 + ((lu >> 4) << 3);
    short8 hh, mm;
    splitf8(*(const float4*)p, *(const float4*)(p + 4), hh, mm);
    const int off = (q * 64 + lu) * 8;
    *(short8*)(xph + off) = hh;
    *(short8*)(xpm + off) = mm;
  }
  __syncthreads();

  // ---- layer1: h1 = tanh(x @ W1^T + b1), N=512; wave owns 4 j-tiles ----
  f32x4 acc1[4];
#pragma unroll
  for (int jj = 0; jj < 4; ++jj) acc1[jj] = (f32x4){0.f, 0.f, 0.f, 0.f};
#pragma unroll 4
  for (int q = 0; q < 8; ++q) {
    const int aoff = (q * 64 + lane) * 8;
    const short8 Ah = *(const short8*)(xph + aoff);
    const short8 Am = *(const short8*)(xpm + aoff);
#pragma unroll
    for (int jj = 0; jj < 4; ++jj) {
      const int boff = (((wave * 4 + jj) * 8 + q) * 64 + lane) * 8;
      const short8 Bh = *(const short8*)(w1h + boff);
      const short8 Bm = *(const short8*)(w1m + boff);
      acc1[jj] = __builtin_amdgcn_mfma_f32_16x16x32_bf16(Ah, Bh, acc1[jj], 0, 0, 0);
      acc1[jj] = __builtin_amdgcn_mfma_f32_16x16x32_bf16(Ah, Bm, acc1[jj], 0, 0, 0);
      acc1[jj] = __builtin_amdgcn_mfma_f32_16x16x32_bf16(Am, Bh, acc1[jj], 0, 0, 0);
    }
  }
  __syncthreads();   // xp dead; [0,16K) becomes wbuf1

  // ---- L1 epilogue: two 256-col halves through swizzled wbuf1 ----
  float bv1[4];
#pragma unroll
  for (int jj = 0; jj < 4; ++jj) bv1[jj] = b1[(wave * 4 + jj) * 16 + col16];
#pragma unroll
  for (int h = 0; h < 2; ++h) {
    if ((wave >> 2) == h) {
#pragma unroll
      for (int jj = 0; jj < 4; ++jj)
#pragma unroll
        for (int r = 0; r < 4; ++r) {
          const int row = rbase + r;
          const int col = ((wave & 3) * 4 + jj) * 16 + col16;   // [0,256)
          wbuf1[(row * 256 + col) ^ ((row & 7) << 2)] = tanh_fast(acc1[jj][r] + bv1[jj]);
        }
    }
    __syncthreads();
    {
      const int lu = tid & 63, ql = tid >> 6;
      const int row = lu & 15, kl = ql * 32 + ((lu >> 4) << 3);
      float4 a, b;
      rd8_swz(wbuf1, 256, row, kl, a, b);
      short8 hh, mm;
      splitf8(a, b, hh, mm);
      const int off = ((h * 8 + ql) * 64 + lu) * 8;
      *(short8*)(h1h + off) = hh;
      *(short8*)(h1m + off) = mm;
    }
    __syncthreads();
  }

  // ---- layer2: h2 = tanh(h1 @ W2^T + b2), N=256; wave owns 2 j-tiles ----
  f32x4 acc2[2];
#pragma unroll
  for (int jj = 0; jj < 2; ++jj) acc2[jj] = (f32x4){0.f, 0.f, 0.f, 0.f};
#pragma unroll 4
  for (int q = 0; q < 16; ++q) {
    const int aoff = (q * 64 + lane) * 8;
    const short8 Ah = *(const short8*)(h1h + aoff);
    const short8 Am = *(const short8*)(h1m + aoff);
#pragma unroll
    for (int jj = 0; jj < 2; ++jj) {
      const int boff = (((wave * 2 + jj) * 16 + q) * 64 + lane) * 8;
      const short8 Bh = *(const short8*)(w2h + boff);
      const short8 Bm = *(const short8*)(w2m + boff);
      acc2[jj] = __builtin_amdgcn_mfma_f32_16x16x32_bf16(Ah, Bh, acc2[jj], 0, 0, 0);
      acc2[jj] = __builtin_amdgcn_mfma_f32_16x16x32_bf16(Ah, Bm, acc2[jj], 0, 0, 0);
      acc2[jj] = __builtin_amdgcn_mfma_f32_16x16x32_bf16(Am, Bh, acc2[jj], 0, 0, 0);
    }
  }
  __syncthreads();   // h1 dead; [16K,32K) becomes wbuf2

  // ---- L2 epilogue: one pass through swizzled wbuf2 ----
  {
    float bv2[2];
#pragma unroll
    for (int jj = 0; jj < 2; ++jj) bv2[jj] = b2[(wave * 2 + jj) * 16 + col16];
#pragma unroll
    for (int jj = 0; jj < 2; ++jj)
#pragma unroll
      for (int r = 0; r < 4; ++r) {
        const int row = rbase + r;
        const int col = (wave * 2 + jj) * 16 + col16;   // [0,256)
        wbuf2[(row * 256 + col) ^ ((row & 7) << 2)] = tanh_fast(acc2[jj][r] + bv2[jj]);
      }
  }
  __syncthreads();
  {
    const int lu = tid & 63, ql = tid >> 6;
    const int row = lu & 15, kl = ql * 32 + ((lu >> 4) << 3);
    float4 a, b;
    rd8_swz(wbuf2, 256, row, kl, a, b);
    short8 hh, mm;
    splitf8(a, b, hh, mm);
    const int off = (ql * 64 + lu) * 8;
    *(short8*)(h2ph + off) = hh;
    *(short8*)(h2pm + off) = mm;
  }
  __syncthreads();

  // ---- layer3: out = h2 @ W3^T + b3, N=64; waves 0-3 ----
  if (wave < 4) {
    f32x4 acc3 = (f32x4){0.f, 0.f, 0.f, 0.f};
#pragma unroll 4
    for (int q = 0; q < 8; ++q) {
      const int aoff = (q * 64 + lane) * 8;
      const short8 Ah = *(const short8*)(h2ph + aoff);
      const short8 Am = *(const short8*)(h2pm + aoff);
      const int boff = ((wave * 8 + q) * 64 + lane) * 8;
      const short8 Bh = *(const short8*)(w3h + boff);
      const short8 Bm = *(const short8*)(w3m + boff);
      acc3 = __builtin_amdgcn_mfma_f32_16x16x32_bf16(Ah, Bh, acc3, 0, 0, 0);
      acc3 = __builtin_amdgcn_mfma_f32_16x16x32_bf16(Ah, Bm, acc3, 0, 0, 0);
      acc3 = __builtin_amdgcn_mfma_f32_16x16x32_bf16(Am, Bh, acc3, 0, 0, 0);
    }
    const float bv3 = b3[wave * 16 + col16];
#pragma unroll
    for (int r = 0; r < 4; ++r) {
      const int row = rbase + r;
      const int col = wave * 16 + col16;   // [0,64)
      wbuf3[(row * 64 + col) ^ ((row & 7) << 2)] = acc3[r] + bv3;
    }
  }
  __syncthreads();

  // ---- row norms: 16 threads/row x 4 cols ----
  if (tid < 256) {
    const int row = tid >> 4, c4 = (tid & 15) * 4;
    const float4 a = *(const float4*)&wbuf3[(row * 64 + c4) ^ ((row & 7) << 2)];
    float s = a.x * a.x + a.y * a.y + a.z * a.z + a.w * a.w;
    s += __shfl_xor(s, 1, 64);
    s += __shfl_xor(s, 2, 64);
    s += __shfl_xor(s, 4, 64);
    s += __shfl_xor(s, 8, 64);
    if ((tid & 15) == 0) nsum[row] = s;
  }
  __syncthreads();
  if (tid < 16) invn[tid] = 1.0f / (sqrtf(nsum[tid]) + EPSF);
  __syncthreads();

  // ---- write out (fp32) ----
  if (tid < 256) {
    const int row = tid >> 4, c4 = (tid & 15) * 4;
    *(float4*)(out + (size_t)(r0 + row) * D_OUT + c4) =
        *(const float4*)&wbuf3[(row * 64 + c4) ^ ((row & 7) << 2)];
  }
  // ---- write normalized split-pack vph/vpm (gram operand) ----
  if (tid < 128) {
    const int lu = tid & 63, ql = tid >> 6;
    const int row = lu & 15, kl = ql * 32 + ((lu >> 4) << 3);
    const float sc = invn[row];
    float4 a, b;
    rd8_swz(wbuf3, 64, row, kl, a, b);
    a.x *= sc; a.y *= sc; a.z *= sc; a.w *= sc;
    b.x *= sc; b.y *= sc; b.z *= sc; b.w *= sc;
    short8 hh, mm;
    splitf8(a, b, hh, mm);
    const size_t off = (((size_t)blockIdx.x * 2 + ql) * 64 + lu) * 8;
    *(short8*)(vph + off) = hh;
    *(short8*)(vpm + off) = mm;
  }
}

// ---------------- MFMA Gram -> adjacency BITMAP (v7, no atomics) ----------------
// bm[row][chunk] (ushort, 512 chunks/row, 8 MB total): bit b of chunk c of row
// i <=> adjacency(i, c*16+b).  Triangular block (I,Jc) exclusively owns bitmap
// regions rows[i0,+128) x chunks[Jc*8,+8) (i-dir) and rows[j0c,+128) x
// chunks[I*8,+8) (j-dir) -> plain stores, full coverage, each word written
// once.  Off-diag: both dirs derive from the SAME ballot -> symmetric bits.
// Diag (I==Jc): i-dir alone covers the whole region (j-dir store skipped).
__global__ __launch_bounds__(256, 4)
void gram_bits(const short* __restrict__ vph, const short* __restrict__ vpm,
               unsigned short* __restrict__ bm) {
  __shared__ __align__(16) short lAh[8 * 1024];       // 16 KB: A hi, 8 i-tiles
  __shared__ __align__(16) unsigned short ci[128 * 8];  // 2 KB i-dir chunks
  __shared__ __align__(16) unsigned short cj[128 * 8];  // 2 KB j-dir chunks
  const int tid = threadIdx.x;
  const int wave = tid >> 6, lane = tid & 63;

  // triangular decode: block t -> (I, Jc) with 0 <= I <= Jc < 64
  const int t = blockIdx.x;
  int I = (int)((129.0f - sqrtf(16641.0f - 8.0f * (float)t)) * 0.5f);
  if (I < 0) I = 0;
  while (64 * (I + 1) - ((I + 1) * I) / 2 <= t) ++I;
  while (64 * I - (I * (I - 1)) / 2 > t) --I;
  const int Jc = I + (t - (64 * I - (I * (I - 1)) / 2));
  const int i0 = I * 128;    // 8 i-tiles
  const int j0c = Jc * 128;  // 8 j-tiles

  // stage A-hi for the 8 i-tiles (16 KB)
  {
    const size_t base = (size_t)I * 8192;
#pragma unroll
    for (int u = 0; u < 4; ++u) {
      const int item = wave * 4 + u;
      __builtin_amdgcn_global_load_lds(
          (const __attribute__((address_space(1))) void*)(vph + base + item * 512 + lane * 8),
          (__attribute__((address_space(3))) void*)(lAh + item * 512), 16, 0, 0);
    }
  }
  __syncthreads();

  const int jloc = lane & 15;

#pragma unroll
  for (int tt = 0; tt < 2; ++tt) {
    const int jt = wave * 2 + tt;
    const int j0 = j0c + jt * 16;
    const short* jb_h = vph + (size_t)(j0 >> 4) * 1024;
    short8 Bh0 = *(const short8*)(jb_h + lane * 8);
    short8 Bh1 = *(const short8*)(jb_h + 512 + lane * 8);

    f32x4 g[8];
#pragma unroll
    for (int it = 0; it < 8; ++it) g[it] = (f32x4){0.f, 0.f, 0.f, 0.f};
    // hh screen: 16 MFMAs, 8 independent chains; A read from LDS at use
#pragma unroll
    for (int it = 0; it < 8; ++it) {
      const short8 A0 = *(const short8*)(lAh + it * 1024 + lane * 8);
      g[it] = __builtin_amdgcn_mfma_f32_16x16x32_bf16(A0, Bh0, g[it], 0, 0, 0);
    }
#pragma unroll
    for (int it = 0; it < 8; ++it) {
      const short8 A1 = *(const short8*)(lAh + it * 1024 + 512 + lane * 8);
      g[it] = __builtin_amdgcn_mfma_f32_16x16x32_bf16(A1, Bh1, g[it], 0, 0, 0);
    }

    bool band = false;
#pragma unroll
    for (int it = 0; it < 8; ++it)
#pragma unroll
      for (int r = 0; r < 4; ++r) {
        const float f = g[it][r] * g[it][r];
        band = band || (f > BAND_LO && f < BAND_HI);
      }
    if (__any(band)) {
      // exact refine: add hi*mid + mid*hi terms (A-mid from global, rare path)
      const short* jb_m = vpm + (size_t)(j0 >> 4) * 1024;
      short8 Bm0 = *(const short8*)(jb_m + lane * 8);
      short8 Bm1 = *(const short8*)(jb_m + 512 + lane * 8);
#pragma unroll
      for (int it = 0; it < 8; ++it) {
        const short8 A0 = *(const short8*)(lAh + it * 1024 + lane * 8);
        const short8 A1 = *(const short8*)(lAh + it * 1024 + 512 + lane * 8);
        g[it] = __builtin_amdgcn_mfma_f32_16x16x32_bf16(A0, Bm0, g[it], 0, 0, 0);
        g[it] = __builtin_amdgcn_mfma_f32_16x16x32_bf16(A1, Bm1, g[it], 0, 0, 0);
        const size_t abase = (size_t)((i0 >> 4) + it) * 1024;
        const short8 Am0 = *(const short8*)(vpm + abase + lane * 8);
        const short8 Am1 = *(const short8*)(vpm + abase + 512 + lane * 8);
        g[it] = __builtin_amdgcn_mfma_f32_16x16x32_bf16(Am0, Bh0, g[it], 0, 0, 0);
        g[it] = __builtin_amdgcn_mfma_f32_16x16x32_bf16(Am1, Bh1, g[it], 0, 0, 0);
      }
    }

    // ballot -> bitmap chunks (both directions from the same ballot)
    const int jl = j0 + jloc;
#pragma unroll
    for (int it = 0; it < 8; ++it) {
      unsigned int t16 = 0;
#pragma unroll
      for (int r = 0; r < 4; ++r) {
        const int il = i0 + it * 16 + (lane >> 4) * 4 + r;
        const unsigned long long m =
            __ballot((g[it][r] * g[it][r] >= THRESH) && (il != jl));
        // i-dir: row (it, g4=lane, r), chunk jt ; 16 bits = (m >> g4*16)
        if (lane < 4)
          ci[(it * 16 + lane * 4 + r) * 8 + jt] =
              (unsigned short)((m >> (lane * 16)) & 0xFFFFu);
        // j-dir: row (jt, jloc), chunk it ; bit b = g4*4+r
        t16 |= ((unsigned int)((m >> jloc) & 1ull)) << r;
        t16 |= ((unsigned int)((m >> (16 + jloc)) & 1ull)) << (4 + r);
        t16 |= ((unsigned int)((m >> (32 + jloc)) & 1ull)) << (8 + r);
        t16 |= ((unsigned int)((m >> (48 + jloc)) & 1ull)) << (12 + r);
      }
      if (lane < 16) cj[(jt * 16 + jloc) * 8 + it] = (unsigned short)t16;
    }
  }
  __syncthreads();

  // flush chunks: one 16B store per row per direction
  if (tid < 128) {
    const uint4 v = *(const uint4*)&ci[tid * 8];
    *(uint4*)((char*)bm + (size_t)(i0 + tid) * 1024 + (size_t)Jc * 16) = v;
  } else if (I != Jc) {
    const int lj = tid - 128;
    const uint4 v = *(const uint4*)&cj[lj * 8];
    *(uint4*)((char*)bm + (size_t)(j0c + lj) * 1024 + (size_t)I * 16) = v;
  }
}

// ---------------- bitmap-driven gather: res[i] = sum_{bit j} out[j] ----------------
// one wave per row; lane k owns out-element k.  Row bits read as 64 x 16B
// same-address broadcast loads; set bits -> coalesced 256B gathers of out
// (L2-resident).  No atomics; res written directly (overwrites poison).
__global__ __launch_bounds__(256, 8)
void bitsum(const ulonglong2* __restrict__ bm, const float* __restrict__ out,
            float* __restrict__ res) {
  const int wave = threadIdx.x >> 6, lane = threadIdx.x & 63;
  const int row = blockIdx.x * 4 + wave;
  const ulonglong2* rw = bm + (size_t)row * 64;   // 64 x 16B = 1KB row bits
  float acc = 0.f;
  for (int w = 0; w < 64; ++w) {
    ulonglong2 v = rw[w];           // same addr across lanes -> broadcast
    unsigned long long word = v.x;
    int jb = w * 128;
    while (word) {
      const int b = __builtin_ctzll(word);
      word &= word - 1;
      acc += out[(size_t)(jb + b) * D_OUT + lane];
    }
    word = v.y;
    jb += 64;
    while (word) {
      const int b = __builtin_ctzll(word);
      word &= word - 1;
      acc += out[(size_t)(jb + b) * D_OUT + lane];
    }
  }
  res[(size_t)row * D_OUT + lane] = acc;
}

// ---------------- launch ----------------
#define MB (1024 * 1024)
#define KB 1024

extern "C" void kernel_launch(void* const* d_in, const int* in_sizes, int n_in,
                              void* d_out, int out_size, void* d_ws, size_t ws_size,
                              hipStream_t stream) {
  const float* x  = (const float*)d_in[0];
  const float* W1 = (const float*)d_in[1];
  const float* b1 = (const float*)d_in[2];
  const float* W2 = (const float*)d_in[3];
  const float* b2 = (const float*)d_in[4];
  const float* W3 = (const float*)d_in[5];
  const float* b3 = (const float*)d_in[6];
  float* res = (float*)d_out;

  char* ws = (char*)d_ws;
  float* out = (float*)(ws);                     // 2 MB
  short* vph = (short*)(ws + 2 * MB);            // 1 MB
  short* vpm = (short*)(ws + 3 * MB);            // 1 MB
  short* w1h = (short*)(ws + 4 * MB);            // 256 KB
  short* w1m = (short*)(ws + 4 * MB + 256 * KB);
  short* w2h = (short*)(ws + 4 * MB + 512 * KB);
  short* w2m = (short*)(ws + 4 * MB + 768 * KB);
  short* w3h = (short*)(ws + 5 * MB);            // 32 KB
  short* w3m = (short*)(ws + 5 * MB + 32 * KB);
  unsigned short* bmap = (unsigned short*)(ws + 6 * MB);   // 8 MB bitmap

  // pack weights to fragment-major bf16 hi/mid (tiny, ~2.2 MB rw)
  wpack<<<136, 256, 0, stream>>>(W1, W2, W3, w1h, w1m, w2h, w2m, w3h, w3m);
  // fused MLP: 512 x 16-row blocks, 2 blocks/CU (round-3 config)
  fused_mlp16<<<512, 512, 0, stream>>>(x, w1h, w1m, b1, w2h, w2m, b2,
                                       w3h, w3m, b3, out, vph, vpm);
  // gram v7: triangular superblocks -> adjacency bitmap, plain stores
  gram_bits<<<dim3(2080), 256, 0, stream>>>(vph, vpm, bmap);
  // bitmap-driven gather (no atomics), writes res directly
  bitsum<<<dim3(B_ROWS / 4), 256, 0, stream>>>((const ulonglong2*)bmap, out, res);
}

// Round 6
// 145.481 us; speedup vs baseline: 1.0359x; 1.0359x over previous
//
#include <hip/hip_runtime.h>
#include <hip/hip_bf16.h>
#include <math.h>

// Problem dims (fixed by reference)
#define B_ROWS 8192
#define D_IN   256
#define H1_DIM 512
#define H2_DIM 256
#define D_OUT  64
#define EPSF   1e-12f
#define THRESH 0.9f
// hh-only gram screen: |fid_hh - fid_true| < 0.008 for unit vectors
// -> decisions outside (0.89, 0.91) are certain; band hits get exact refine.
#define BAND_LO 0.89f
#define BAND_HI 0.91f

typedef __attribute__((ext_vector_type(8))) short short8;   // 8 bf16 = 4 VGPR
typedef __attribute__((ext_vector_type(4))) float f32x4;

// fast tanh via hardware exp: tanh(|x|) = (1-e^{-2|x|})/(1+e^{-2|x|}), ~1e-7 rel err
__device__ inline float tanh_fast(float xx) {
  const float ax = fabsf(xx);
  const float t = __expf(-2.0f * ax);
  const float r = (1.0f - t) / (1.0f + t);
  return xx < 0.0f ? -r : r;
}

// split fp32x8 -> bf16 hi + bf16 mid (residual), fragment-packed
__device__ inline void splitf8(float4 a, float4 b, short8& h, short8& m) {
  float v[8] = {a.x, a.y, a.z, a.w, b.x, b.y, b.z, b.w};
  short h8[8], m8[8];
#pragma unroll
  for (int e = 0; e < 8; ++e) {
    __hip_bfloat16 hb = __float2bfloat16(v[e]);
    float hf = __bfloat162float(hb);
    __hip_bfloat16 mb = __float2bfloat16(v[e] - hf);
    h8[e] = *(short*)&hb;
    m8[e] = *(short*)&mb;
  }
  h = *(short8*)h8;
  m = *(short8*)m8;
}

// read 8 logical-consecutive floats at (row, kl) from an XOR-swizzled LDS buf.
// swizzle: dword index ^= (row&7)<<2 (16B-slot spread -> conflict-free b128)
__device__ inline void rd8_swz(const float* buf, int S, int row, int kl,
                               float4& a, float4& b) {
  const int xr = (row & 7) << 2;
  a = *(const float4*)&buf[(row * S + kl) ^ xr];
  b = *(const float4*)&buf[(row * S + kl + 4) ^ xr];
}

// ---------------- weight pre-pack (fragment-major bf16 hi/mid) ----------------
__device__ inline void pack8(const float* __restrict__ src, short* __restrict__ dh,
                             short* __restrict__ dm, int t, int C, int lgq) {
  const int lane = t & 63;
  const int g = t >> 6;
  const int q = g & ((1 << lgq) - 1);
  const int I = g >> lgq;
  const int row = I * 16 + (lane & 15);
  const int k0 = q * 32 + ((lane >> 4) << 3);
  const float* p = src + (size_t)row * C + k0;
  short8 hh, mm;
  splitf8(*(const float4*)p, *(const float4*)(p + 4), hh, mm);
  *(short8*)(dh + (size_t)t * 8) = hh;
  *(short8*)(dm + (size_t)t * 8) = mm;
}

__global__ __launch_bounds__(256)
void wpack(const float* __restrict__ W1, const float* __restrict__ W2,
           const float* __restrict__ W3,
           short* w1h, short* w1m, short* w2h, short* w2m,
           short* w3h, short* w3m) {
  const int b = blockIdx.x, tid = threadIdx.x;
  if (b < 64)        pack8(W1, w1h, w1m, b * 256 + tid, 256, 3);
  else if (b < 128)  pack8(W2, w2h, w2m, (b - 64) * 256 + tid, 512, 4);
  else               pack8(W3, w3h, w3m, (b - 128) * 256 + tid, 256, 3);
}

// ---------------- fully fused MLP, 16-row blocks (round-3 config) ----------------
__global__ __launch_bounds__(512, 4)
void fused_mlp16(const float* __restrict__ x,
                 const short* __restrict__ w1h, const short* __restrict__ w1m,
                 const float* __restrict__ b1,
                 const short* __restrict__ w2h, const short* __restrict__ w2m,
                 const float* __restrict__ b2,
                 const short* __restrict__ w3h, const short* __restrict__ w3m,
                 const float* __restrict__ b3,
                 float* __restrict__ out, short* __restrict__ vph,
                 short* __restrict__ vpm) {
  __shared__ __align__(16) char smem[49152];
  short* xph   = (short*)smem;                // 8KB
  short* xpm   = (short*)(smem + 8192);       // 8KB
  float* wbuf1 = (float*)smem;                // 16KB
  float* wbuf3 = (float*)smem;                // 4KB
  short* h1h   = (short*)(smem + 16384);      // 16KB
  short* h1m   = (short*)(smem + 32768);      // 16KB
  float* wbuf2 = (float*)(smem + 16384);      // 16KB
  short* h2ph  = (short*)(smem + 32768);      // 8KB
  short* h2pm  = (short*)(smem + 40960);      // 8KB
  __shared__ float nsum[16];
  __shared__ float invn[16];

  const int tid = threadIdx.x;
  const int wave = tid >> 6, lane = tid & 63;
  const int r0 = blockIdx.x * 16;
  const int col16 = lane & 15;
  const int rbase = (lane >> 4) << 2;   // C-layout row base

  // ---- pack x block (16x256 fp32 -> frag hi/mid): 512 units, 1/thread ----
  {
    const int lu = tid & 63, q = tid >> 6;
    const float* p = x + (size_t)(r0 + (lu & 15)) * D_IN + q * 32 + ((lu >> 4) << 3);
    short8 hh, mm;
    splitf8(*(const float4*)p, *(const float4*)(p + 4), hh, mm);
    const int off = (q * 64 + lu) * 8;
    *(short8*)(xph + off) = hh;
    *(short8*)(xpm + off) = mm;
  }
  __syncthreads();

  // ---- layer1: h1 = tanh(x @ W1^T + b1), N=512; wave owns 4 j-tiles ----
  f32x4 acc1[4];
#pragma unroll
  for (int jj = 0; jj < 4; ++jj) acc1[jj] = (f32x4){0.f, 0.f, 0.f, 0.f};
#pragma unroll 4
  for (int q = 0; q < 8; ++q) {
    const int aoff = (q * 64 + lane) * 8;
    const short8 Ah = *(const short8*)(xph + aoff);
    const short8 Am = *(const short8*)(xpm + aoff);
#pragma unroll
    for (int jj = 0; jj < 4; ++jj) {
      const int boff = (((wave * 4 + jj) * 8 + q) * 64 + lane) * 8;
      const short8 Bh = *(const short8*)(w1h + boff);
      const short8 Bm = *(const short8*)(w1m + boff);
      acc1[jj] = __builtin_amdgcn_mfma_f32_16x16x32_bf16(Ah, Bh, acc1[jj], 0, 0, 0);
      acc1[jj] = __builtin_amdgcn_mfma_f32_16x16x32_bf16(Ah, Bm, acc1[jj], 0, 0, 0);
      acc1[jj] = __builtin_amdgcn_mfma_f32_16x16x32_bf16(Am, Bh, acc1[jj], 0, 0, 0);
    }
  }
  __syncthreads();   // xp dead; [0,16K) becomes wbuf1

  // ---- L1 epilogue: two 256-col halves through swizzled wbuf1 ----
  float bv1[4];
#pragma unroll
  for (int jj = 0; jj < 4; ++jj) bv1[jj] = b1[(wave * 4 + jj) * 16 + col16];
#pragma unroll
  for (int h = 0; h < 2; ++h) {
    if ((wave >> 2) == h) {
#pragma unroll
      for (int jj = 0; jj < 4; ++jj)
#pragma unroll
        for (int r = 0; r < 4; ++r) {
          const int row = rbase + r;
          const int col = ((wave & 3) * 4 + jj) * 16 + col16;   // [0,256)
          wbuf1[(row * 256 + col) ^ ((row & 7) << 2)] = tanh_fast(acc1[jj][r] + bv1[jj]);
        }
    }
    __syncthreads();
    {
      const int lu = tid & 63, ql = tid >> 6;
      const int row = lu & 15, kl = ql * 32 + ((lu >> 4) << 3);
      float4 a, b;
      rd8_swz(wbuf1, 256, row, kl, a, b);
      short8 hh, mm;
      splitf8(a, b, hh, mm);
      const int off = ((h * 8 + ql) * 64 + lu) * 8;
      *(short8*)(h1h + off) = hh;
      *(short8*)(h1m + off) = mm;
    }
    __syncthreads();
  }

  // ---- layer2: h2 = tanh(h1 @ W2^T + b2), N=256; wave owns 2 j-tiles ----
  f32x4 acc2[2];
#pragma unroll
  for (int jj = 0; jj < 2; ++jj) acc2[jj] = (f32x4){0.f, 0.f, 0.f, 0.f};
#pragma unroll 4
  for (int q = 0; q < 16; ++q) {
    const int aoff = (q * 64 + lane) * 8;
    const short8 Ah = *(const short8*)(h1h + aoff);
    const short8 Am = *(const short8*)(h1m + aoff);
#pragma unroll
    for (int jj = 0; jj < 2; ++jj) {
      const int boff = (((wave * 2 + jj) * 16 + q) * 64 + lane) * 8;
      const short8 Bh = *(const short8*)(w2h + boff);
      const short8 Bm = *(const short8*)(w2m + boff);
      acc2[jj] = __builtin_amdgcn_mfma_f32_16x16x32_bf16(Ah, Bh, acc2[jj], 0, 0, 0);
      acc2[jj] = __builtin_amdgcn_mfma_f32_16x16x32_bf16(Ah, Bm, acc2[jj], 0, 0, 0);
      acc2[jj] = __builtin_amdgcn_mfma_f32_16x16x32_bf16(Am, Bh, acc2[jj], 0, 0, 0);
    }
  }
  __syncthreads();   // h1 dead; [16K,32K) becomes wbuf2

  // ---- L2 epilogue ----
  {
    float bv2[2];
#pragma unroll
    for (int jj = 0; jj < 2; ++jj) bv2[jj] = b2[(wave * 2 + jj) * 16 + col16];
#pragma unroll
    for (int jj = 0; jj < 2; ++jj)
#pragma unroll
      for (int r = 0; r < 4; ++r) {
        const int row = rbase + r;
        const int col = (wave * 2 + jj) * 16 + col16;   // [0,256)
        wbuf2[(row * 256 + col) ^ ((row & 7) << 2)] = tanh_fast(acc2[jj][r] + bv2[jj]);
      }
  }
  __syncthreads();
  {
    const int lu = tid & 63, ql = tid >> 6;
    const int row = lu & 15, kl = ql * 32 + ((lu >> 4) << 3);
    float4 a, b;
    rd8_swz(wbuf2, 256, row, kl, a, b);
    short8 hh, mm;
    splitf8(a, b, hh, mm);
    const int off = (ql * 64 + lu) * 8;
    *(short8*)(h2ph + off) = hh;
    *(short8*)(h2pm + off) = mm;
  }
  __syncthreads();

  // ---- layer3: out = h2 @ W3^T + b3, N=64; waves 0-3 ----
  if (wave < 4) {
    f32x4 acc3 = (f32x4){0.f, 0.f, 0.f, 0.f};
#pragma unroll 4
    for (int q = 0; q < 8; ++q) {
      const int aoff = (q * 64 + lane) * 8;
      const short8 Ah = *(const short8*)(h2ph + aoff);
      const short8 Am = *(const short8*)(h2pm + aoff);
      const int boff = ((wave * 8 + q) * 64 + lane) * 8;
      const short8 Bh = *(const short8*)(w3h + boff);
      const short8 Bm = *(const short8*)(w3m + boff);
      acc3 = __builtin_amdgcn_mfma_f32_16x16x32_bf16(Ah, Bh, acc3, 0, 0, 0);
      acc3 = __builtin_amdgcn_mfma_f32_16x16x32_bf16(Ah, Bm, acc3, 0, 0, 0);
      acc3 = __builtin_amdgcn_mfma_f32_16x16x32_bf16(Am, Bh, acc3, 0, 0, 0);
    }
    const float bv3 = b3[wave * 16 + col16];
#pragma unroll
    for (int r = 0; r < 4; ++r) {
      const int row = rbase + r;
      const int col = wave * 16 + col16;   // [0,64)
      wbuf3[(row * 64 + col) ^ ((row & 7) << 2)] = acc3[r] + bv3;
    }
  }
  __syncthreads();

  // ---- row norms: 16 threads/row x 4 cols ----
  if (tid < 256) {
    const int row = tid >> 4, c4 = (tid & 15) * 4;
    const float4 a = *(const float4*)&wbuf3[(row * 64 + c4) ^ ((row & 7) << 2)];
    float s = a.x * a.x + a.y * a.y + a.z * a.z + a.w * a.w;
    s += __shfl_xor(s, 1, 64);
    s += __shfl_xor(s, 2, 64);
    s += __shfl_xor(s, 4, 64);
    s += __shfl_xor(s, 8, 64);
    if ((tid & 15) == 0) nsum[row] = s;
  }
  __syncthreads();
  if (tid < 16) invn[tid] = 1.0f / (sqrtf(nsum[tid]) + EPSF);
  __syncthreads();

  // ---- write out (fp32) ----
  if (tid < 256) {
    const int row = tid >> 4, c4 = (tid & 15) * 4;
    *(float4*)(out + (size_t)(r0 + row) * D_OUT + c4) =
        *(const float4*)&wbuf3[(row * 64 + c4) ^ ((row & 7) << 2)];
  }
  // ---- write normalized split-pack vph/vpm (gram operand) ----
  if (tid < 128) {
    const int lu = tid & 63, ql = tid >> 6;
    const int row = lu & 15, kl = ql * 32 + ((lu >> 4) << 3);
    const float sc = invn[row];
    float4 a, b;
    rd8_swz(wbuf3, 64, row, kl, a, b);
    a.x *= sc; a.y *= sc; a.z *= sc; a.w *= sc;
    b.x *= sc; b.y *= sc; b.z *= sc; b.w *= sc;
    short8 hh, mm;
    splitf8(a, b, hh, mm);
    const size_t off = (((size_t)blockIdx.x * 2 + ql) * 64 + lu) * 8;
    *(short8*)(vph + off) = hh;
    *(short8*)(vpm + off) = mm;
  }
}

// ---------------- full Gram, panel-private LDS accumulation (v8) ----------------
// res[i] = sum_{j != i, fid >= 0.9} out[j]
// grid (64 i-panels x 8 j-slices).  Block owns 128 i-rows x 1024 j-cols;
// accumulates res-partials in LDS acc[128][64] via ds_add_f32 (lane k owns
// element k; banks alias 2-way = free), flushes with PLAIN coalesced stores to
// resp[slice] -> NO global atomics.  reduce8 sums the 8 slices.
// Duplicate (i,j)/(j,i) decisions are bitwise-symmetric: screen g is MFMA-
// transpose-symmetric; refine cross terms go to separate accumulators g2a/g2b
// (g2a_ij==g2b_ji bitwise) combined with one commutative f32 add.
__global__ __launch_bounds__(256, 2)
void gram_lds(const short* __restrict__ vph, const short* __restrict__ vpm,
              const float* __restrict__ out, float* __restrict__ resp) {
  __shared__ __align__(16) short lAh[8 * 1024];   // 16 KB: A-hi, 8 i-tiles
  __shared__ __align__(16) float acc[128 * 64];   // 32 KB res partial
  const int tid = threadIdx.x;
  const int wave = tid >> 6, lane = tid & 63;
  const int I = blockIdx.x;        // i-panel [0,64)
  const int sl = blockIdx.y;       // j-slice [0,8)
  const int i0 = I * 128;
  const int jbase = sl * 1024;

  // zero acc (8192 floats = 2048 float4)
#pragma unroll
  for (int u = 0; u < 8; ++u)
    *(float4*)&acc[(u * 256 + tid) * 4] = make_float4(0.f, 0.f, 0.f, 0.f);

  // stage A-hi for the 8 i-tiles (16 KB)
  {
    const size_t base = (size_t)I * 8192;
#pragma unroll
    for (int u = 0; u < 4; ++u) {
      const int item = wave * 4 + u;
      __builtin_amdgcn_global_load_lds(
          (const __attribute__((address_space(1))) void*)(vph + base + item * 512 + lane * 8),
          (__attribute__((address_space(3))) void*)(lAh + item * 512), 16, 0, 0);
    }
  }
  __syncthreads();

  // 64 j-tiles per block, interleaved across 4 waves
  for (int u = 0; u < 16; ++u) {
    const int jt = u * 4 + wave;
    const int j0 = jbase + jt * 16;
    const short* jb_h = vph + (size_t)(j0 >> 4) * 1024;
    const short8 Bh0 = *(const short8*)(jb_h + lane * 8);
    const short8 Bh1 = *(const short8*)(jb_h + 512 + lane * 8);

    f32x4 g[8];
#pragma unroll
    for (int it = 0; it < 8; ++it) g[it] = (f32x4){0.f, 0.f, 0.f, 0.f};
    // hh screen: 16 MFMAs, 8 independent chains; A read from LDS at use
#pragma unroll
    for (int it = 0; it < 8; ++it) {
      const short8 A0 = *(const short8*)(lAh + it * 1024 + lane * 8);
      g[it] = __builtin_amdgcn_mfma_f32_16x16x32_bf16(A0, Bh0, g[it], 0, 0, 0);
    }
#pragma unroll
    for (int it = 0; it < 8; ++it) {
      const short8 A1 = *(const short8*)(lAh + it * 1024 + 512 + lane * 8);
      g[it] = __builtin_amdgcn_mfma_f32_16x16x32_bf16(A1, Bh1, g[it], 0, 0, 0);
    }

    bool band = false;
#pragma unroll
    for (int it = 0; it < 8; ++it)
#pragma unroll
      for (int r = 0; r < 4; ++r) {
        const float f = g[it][r] * g[it][r];
        band = band || (f > BAND_LO && f < BAND_HI);
      }
    if (__any(band)) {
      // refine: cross terms in separate accumulators (bitwise-symmetric)
      const short* jb_m = vpm + (size_t)(j0 >> 4) * 1024;
      const short8 Bm0 = *(const short8*)(jb_m + lane * 8);
      const short8 Bm1 = *(const short8*)(jb_m + 512 + lane * 8);
      f32x4 g2a[8], g2b[8];
#pragma unroll
      for (int it = 0; it < 8; ++it) {
        g2a[it] = (f32x4){0.f, 0.f, 0.f, 0.f};
        g2b[it] = (f32x4){0.f, 0.f, 0.f, 0.f};
      }
#pragma unroll
      for (int it = 0; it < 8; ++it) {
        const short8 A0 = *(const short8*)(lAh + it * 1024 + lane * 8);
        const short8 A1 = *(const short8*)(lAh + it * 1024 + 512 + lane * 8);
        g2a[it] = __builtin_amdgcn_mfma_f32_16x16x32_bf16(A0, Bm0, g2a[it], 0, 0, 0);
        g2a[it] = __builtin_amdgcn_mfma_f32_16x16x32_bf16(A1, Bm1, g2a[it], 0, 0, 0);
        const size_t abase = (size_t)((i0 >> 4) + it) * 1024;
        const short8 Am0 = *(const short8*)(vpm + abase + lane * 8);
        const short8 Am1 = *(const short8*)(vpm + abase + 512 + lane * 8);
        g2b[it] = __builtin_amdgcn_mfma_f32_16x16x32_bf16(Am0, Bh0, g2b[it], 0, 0, 0);
        g2b[it] = __builtin_amdgcn_mfma_f32_16x16x32_bf16(Am1, Bh1, g2b[it], 0, 0, 0);
      }
#pragma unroll
      for (int it = 0; it < 8; ++it)
#pragma unroll
        for (int r = 0; r < 4; ++r)
          g[it][r] += (g2a[it][r] + g2b[it][r]);   // commutative combine
    }

    // ballot -> 4-deep pipelined gather + LDS accumulate
    const int jl = j0 + (lane & 15);
#pragma unroll
    for (int it = 0; it < 8; ++it)
#pragma unroll
      for (int r = 0; r < 4; ++r) {
        const int il = i0 + it * 16 + (lane >> 4) * 4 + r;
        unsigned long long m =
            __ballot((g[it][r] * g[it][r] >= THRESH) && (il != jl));
        while (m) {   // m is wave-uniform -> uniform control flow
          const int s0 = __builtin_ctzll(m); m &= m - 1;
          int s1 = -1, s2 = -1, s3 = -1;
          if (m) { s1 = __builtin_ctzll(m); m &= m - 1; }
          if (m) { s2 = __builtin_ctzll(m); m &= m - 1; }
          if (m) { s3 = __builtin_ctzll(m); m &= m - 1; }
          // issue up to 4 independent coalesced loads, then accumulate
          const float v0 = out[(size_t)(j0 + (s0 & 15)) * D_OUT + lane];
          float v1 = 0.f, v2 = 0.f, v3 = 0.f;
          if (s1 >= 0) v1 = out[(size_t)(j0 + (s1 & 15)) * D_OUT + lane];
          if (s2 >= 0) v2 = out[(size_t)(j0 + (s2 & 15)) * D_OUT + lane];
          if (s3 >= 0) v3 = out[(size_t)(j0 + (s3 & 15)) * D_OUT + lane];
          atomicAdd(&acc[(it * 16 + ((s0 >> 4) << 2) + r) * 64 + lane], v0);
          if (s1 >= 0) atomicAdd(&acc[(it * 16 + ((s1 >> 4) << 2) + r) * 64 + lane], v1);
          if (s2 >= 0) atomicAdd(&acc[(it * 16 + ((s2 >> 4) << 2) + r) * 64 + lane], v2);
          if (s3 >= 0) atomicAdd(&acc[(it * 16 + ((s3 >> 4) << 2) + r) * 64 + lane], v3);
        }
      }
  }
  __syncthreads();

  // flush partials: plain coalesced stores, exclusively-owned region
  float* dst = resp + ((size_t)sl * B_ROWS + i0) * D_OUT;
#pragma unroll
  for (int u = 0; u < 8; ++u) {
    const int e = u * 256 + tid;   // float4 index [0,2048)
    *(float4*)&dst[e * 4] = *(const float4*)&acc[e * 4];
  }
}

// ---------------- sum the 8 slice-partials into res ----------------
__global__ __launch_bounds__(256)
void reduce8(const float4* __restrict__ resp, float4* __restrict__ res) {
  const int idx = blockIdx.x * 256 + threadIdx.x;   // [0, 131072)
  float4 a = resp[idx];
#pragma unroll
  for (int s = 1; s < 8; ++s) {
    const float4 b = resp[(size_t)s * (B_ROWS * D_OUT / 4) + idx];
    a.x += b.x; a.y += b.y; a.z += b.z; a.w += b.w;
  }
  res[idx] = a;
}

// ---------------- launch ----------------
#define MB (1024 * 1024)
#define KB 1024

extern "C" void kernel_launch(void* const* d_in, const int* in_sizes, int n_in,
                              void* d_out, int out_size, void* d_ws, size_t ws_size,
                              hipStream_t stream) {
  const float* x  = (const float*)d_in[0];
  const float* W1 = (const float*)d_in[1];
  const float* b1 = (const float*)d_in[2];
  const float* W2 = (const float*)d_in[3];
  const float* b2 = (const float*)d_in[4];
  const float* W3 = (const float*)d_in[5];
  const float* b3 = (const float*)d_in[6];
  float* res = (float*)d_out;

  char* ws = (char*)d_ws;
  float* out = (float*)(ws);                     // 2 MB
  short* vph = (short*)(ws + 2 * MB);            // 1 MB
  short* vpm = (short*)(ws + 3 * MB);            // 1 MB
  short* w1h = (short*)(ws + 4 * MB);            // 256 KB
  short* w1m = (short*)(ws + 4 * MB + 256 * KB);
  short* w2h = (short*)(ws + 4 * MB + 512 * KB);
  short* w2m = (short*)(ws + 4 * MB + 768 * KB);
  short* w3h = (short*)(ws + 5 * MB);            // 32 KB
  short* w3m = (short*)(ws + 5 * MB + 32 * KB);
  float* resp = (float*)(ws + 6 * MB);           // 16 MB partials (8 slices)

  // pack weights to fragment-major bf16 hi/mid (tiny, ~2.2 MB rw)
  wpack<<<136, 256, 0, stream>>>(W1, W2, W3, w1h, w1m, w2h, w2m, w3h, w3m);
  // fused MLP: 512 x 16-row blocks, 2 blocks/CU
  fused_mlp16<<<512, 512, 0, stream>>>(x, w1h, w1m, b1, w2h, w2m, b2,
                                       w3h, w3m, b3, out, vph, vpm);
  // gram v8: full Gram, panel-private LDS accumulation, no global atomics
  gram_lds<<<dim3(64, 8), 256, 0, stream>>>(vph, vpm, out, resp);
  // sum the 8 slice-partials (overwrites res poison)
  reduce8<<<dim3(B_ROWS * D_OUT / 4 / 256), 256, 0, stream>>>(
      (const float4*)resp, (float4*)res);
}

// Round 7
// 132.951 us; speedup vs baseline: 1.1335x; 1.0942x over previous
//
#include <hip/hip_runtime.h>
#include <hip/hip_bf16.h>
#include <math.h>

// Problem dims (fixed by reference)
#define B_ROWS 8192
#define D_IN   256
#define H1_DIM 512
#define H2_DIM 256
#define D_OUT  64
#define EPSF   1e-12f
#define THRESH 0.9f
// hh-only gram screen: |fid_hh - fid_true| < 0.008 for unit vectors
// -> decisions outside (0.89, 0.91) are certain; band hits get exact refine.
#define BAND_LO 0.89f
#define BAND_HI 0.91f

typedef __attribute__((ext_vector_type(8))) short short8;   // 8 bf16 = 4 VGPR
typedef __attribute__((ext_vector_type(4))) float f32x4;

// fast tanh via hardware exp: tanh(|x|) = (1-e^{-2|x|})/(1+e^{-2|x|}), ~1e-7 rel err
__device__ inline float tanh_fast(float xx) {
  const float ax = fabsf(xx);
  const float t = __expf(-2.0f * ax);
  const float r = (1.0f - t) / (1.0f + t);
  return xx < 0.0f ? -r : r;
}

// split fp32x8 -> bf16 hi + bf16 mid (residual), fragment-packed
__device__ inline void splitf8(float4 a, float4 b, short8& h, short8& m) {
  float v[8] = {a.x, a.y, a.z, a.w, b.x, b.y, b.z, b.w};
  short h8[8], m8[8];
#pragma unroll
  for (int e = 0; e < 8; ++e) {
    __hip_bfloat16 hb = __float2bfloat16(v[e]);
    float hf = __bfloat162float(hb);
    __hip_bfloat16 mb = __float2bfloat16(v[e] - hf);
    h8[e] = *(short*)&hb;
    m8[e] = *(short*)&mb;
  }
  h = *(short8*)h8;
  m = *(short8*)m8;
}

// read 8 logical-consecutive floats at (row, kl) from an XOR-swizzled LDS buf.
// swizzle: dword index ^= (row&7)<<2 (16B-slot spread -> conflict-free b128)
__device__ inline void rd8_swz(const float* buf, int S, int row, int kl,
                               float4& a, float4& b) {
  const int xr = (row & 7) << 2;
  a = *(const float4*)&buf[(row * S + kl) ^ xr];
  b = *(const float4*)&buf[(row * S + kl + 4) ^ xr];
}

// ---------------- weight pre-pack (fragment-major bf16 hi/mid) ----------------
__device__ inline void pack8(const float* __restrict__ src, short* __restrict__ dh,
                             short* __restrict__ dm, int t, int C, int lgq) {
  const int lane = t & 63;
  const int g = t >> 6;
  const int q = g & ((1 << lgq) - 1);
  const int I = g >> lgq;
  const int row = I * 16 + (lane & 15);
  const int k0 = q * 32 + ((lane >> 4) << 3);
  const float* p = src + (size_t)row * C + k0;
  short8 hh, mm;
  splitf8(*(const float4*)p, *(const float4*)(p + 4), hh, mm);
  *(short8*)(dh + (size_t)t * 8) = hh;
  *(short8*)(dm + (size_t)t * 8) = mm;
}

__global__ __launch_bounds__(256)
void wpack(const float* __restrict__ W1, const float* __restrict__ W2,
           const float* __restrict__ W3,
           short* w1h, short* w1m, short* w2h, short* w2m,
           short* w3h, short* w3m) {
  const int b = blockIdx.x, tid = threadIdx.x;
  if (b < 64)        pack8(W1, w1h, w1m, b * 256 + tid, 256, 3);
  else if (b < 128)  pack8(W2, w2h, w2m, (b - 64) * 256 + tid, 512, 4);
  else               pack8(W3, w3h, w3m, (b - 128) * 256 + tid, 256, 3);
}

// ---------------- fully fused MLP, 16-row blocks (round-3 config, unchanged) ----------------
__global__ __launch_bounds__(512, 4)
void fused_mlp16(const float* __restrict__ x,
                 const short* __restrict__ w1h, const short* __restrict__ w1m,
                 const float* __restrict__ b1,
                 const short* __restrict__ w2h, const short* __restrict__ w2m,
                 const float* __restrict__ b2,
                 const short* __restrict__ w3h, const short* __restrict__ w3m,
                 const float* __restrict__ b3,
                 float* __restrict__ out, short* __restrict__ vph,
                 short* __restrict__ vpm) {
  __shared__ __align__(16) char smem[49152];
  short* xph   = (short*)smem;                // 8KB
  short* xpm   = (short*)(smem + 8192);       // 8KB
  float* wbuf1 = (float*)smem;                // 16KB
  float* wbuf3 = (float*)smem;                // 4KB
  short* h1h   = (short*)(smem + 16384);      // 16KB
  short* h1m   = (short*)(smem + 32768);      // 16KB
  float* wbuf2 = (float*)(smem + 16384);      // 16KB
  short* h2ph  = (short*)(smem + 32768);      // 8KB
  short* h2pm  = (short*)(smem + 40960);      // 8KB
  __shared__ float nsum[16];
  __shared__ float invn[16];

  const int tid = threadIdx.x;
  const int wave = tid >> 6, lane = tid & 63;
  const int r0 = blockIdx.x * 16;
  const int col16 = lane & 15;
  const int rbase = (lane >> 4) << 2;   // C-layout row base

  // ---- pack x block (16x256 fp32 -> frag hi/mid): 512 units, 1/thread ----
  {
    const int lu = tid & 63, q = tid >> 6;
    const float* p = x + (size_t)(r0 + (lu & 15)) * D_IN + q * 32 + ((lu >> 4) << 3);
    short8 hh, mm;
    splitf8(*(const float4*)p, *(const float4*)(p + 4), hh, mm);
    const int off = (q * 64 + lu) * 8;
    *(short8*)(xph + off) = hh;
    *(short8*)(xpm + off) = mm;
  }
  __syncthreads();

  // ---- layer1: h1 = tanh(x @ W1^T + b1), N=512; wave owns 4 j-tiles ----
  f32x4 acc1[4];
#pragma unroll
  for (int jj = 0; jj < 4; ++jj) acc1[jj] = (f32x4){0.f, 0.f, 0.f, 0.f};
#pragma unroll 4
  for (int q = 0; q < 8; ++q) {
    const int aoff = (q * 64 + lane) * 8;
    const short8 Ah = *(const short8*)(xph + aoff);
    const short8 Am = *(const short8*)(xpm + aoff);
#pragma unroll
    for (int jj = 0; jj < 4; ++jj) {
      const int boff = (((wave * 4 + jj) * 8 + q) * 64 + lane) * 8;
      const short8 Bh = *(const short8*)(w1h + boff);
      const short8 Bm = *(const short8*)(w1m + boff);
      acc1[jj] = __builtin_amdgcn_mfma_f32_16x16x32_bf16(Ah, Bh, acc1[jj], 0, 0, 0);
      acc1[jj] = __builtin_amdgcn_mfma_f32_16x16x32_bf16(Ah, Bm, acc1[jj], 0, 0, 0);
      acc1[jj] = __builtin_amdgcn_mfma_f32_16x16x32_bf16(Am, Bh, acc1[jj], 0, 0, 0);
    }
  }
  __syncthreads();   // xp dead; [0,16K) becomes wbuf1

  // ---- L1 epilogue: two 256-col halves through swizzled wbuf1 ----
  float bv1[4];
#pragma unroll
  for (int jj = 0; jj < 4; ++jj) bv1[jj] = b1[(wave * 4 + jj) * 16 + col16];
#pragma unroll
  for (int h = 0; h < 2; ++h) {
    if ((wave >> 2) == h) {
#pragma unroll
      for (int jj = 0; jj < 4; ++jj)
#pragma unroll
        for (int r = 0; r < 4; ++r) {
          const int row = rbase + r;
          const int col = ((wave & 3) * 4 + jj) * 16 + col16;   // [0,256)
          wbuf1[(row * 256 + col) ^ ((row & 7) << 2)] = tanh_fast(acc1[jj][r] + bv1[jj]);
        }
    }
    __syncthreads();
    {
      const int lu = tid & 63, ql = tid >> 6;
      const int row = lu & 15, kl = ql * 32 + ((lu >> 4) << 3);
      float4 a, b;
      rd8_swz(wbuf1, 256, row, kl, a, b);
      short8 hh, mm;
      splitf8(a, b, hh, mm);
      const int off = ((h * 8 + ql) * 64 + lu) * 8;
      *(short8*)(h1h + off) = hh;
      *(short8*)(h1m + off) = mm;
    }
    __syncthreads();
  }

  // ---- layer2: h2 = tanh(h1 @ W2^T + b2), N=256; wave owns 2 j-tiles ----
  f32x4 acc2[2];
#pragma unroll
  for (int jj = 0; jj < 2; ++jj) acc2[jj] = (f32x4){0.f, 0.f, 0.f, 0.f};
#pragma unroll 4
  for (int q = 0; q < 16; ++q) {
    const int aoff = (q * 64 + lane) * 8;
    const short8 Ah = *(const short8*)(h1h + aoff);
    const short8 Am = *(const short8*)(h1m + aoff);
#pragma unroll
    for (int jj = 0; jj < 2; ++jj) {
      const int boff = (((wave * 2 + jj) * 16 + q) * 64 + lane) * 8;
      const short8 Bh = *(const short8*)(w2h + boff);
      const short8 Bm = *(const short8*)(w2m + boff);
      acc2[jj] = __builtin_amdgcn_mfma_f32_16x16x32_bf16(Ah, Bh, acc2[jj], 0, 0, 0);
      acc2[jj] = __builtin_amdgcn_mfma_f32_16x16x32_bf16(Ah, Bm, acc2[jj], 0, 0, 0);
      acc2[jj] = __builtin_amdgcn_mfma_f32_16x16x32_bf16(Am, Bh, acc2[jj], 0, 0, 0);
    }
  }
  __syncthreads();   // h1 dead; [16K,32K) becomes wbuf2

  // ---- L2 epilogue ----
  {
    float bv2[2];
#pragma unroll
    for (int jj = 0; jj < 2; ++jj) bv2[jj] = b2[(wave * 2 + jj) * 16 + col16];
#pragma unroll
    for (int jj = 0; jj < 2; ++jj)
#pragma unroll
      for (int r = 0; r < 4; ++r) {
        const int row = rbase + r;
        const int col = (wave * 2 + jj) * 16 + col16;   // [0,256)
        wbuf2[(row * 256 + col) ^ ((row & 7) << 2)] = tanh_fast(acc2[jj][r] + bv2[jj]);
      }
  }
  __syncthreads();
  {
    const int lu = tid & 63, ql = tid >> 6;
    const int row = lu & 15, kl = ql * 32 + ((lu >> 4) << 3);
    float4 a, b;
    rd8_swz(wbuf2, 256, row, kl, a, b);
    short8 hh, mm;
    splitf8(a, b, hh, mm);
    const int off = (ql * 64 + lu) * 8;
    *(short8*)(h2ph + off) = hh;
    *(short8*)(h2pm + off) = mm;
  }
  __syncthreads();

  // ---- layer3: out = h2 @ W3^T + b3, N=64; waves 0-3 ----
  if (wave < 4) {
    f32x4 acc3 = (f32x4){0.f, 0.f, 0.f, 0.f};
#pragma unroll 4
    for (int q = 0; q < 8; ++q) {
      const int aoff = (q * 64 + lane) * 8;
      const short8 Ah = *(const short8*)(h2ph + aoff);
      const short8 Am = *(const short8*)(h2pm + aoff);
      const int boff = ((wave * 8 + q) * 64 + lane) * 8;
      const short8 Bh = *(const short8*)(w3h + boff);
      const short8 Bm = *(const short8*)(w3m + boff);
      acc3 = __builtin_amdgcn_mfma_f32_16x16x32_bf16(Ah, Bh, acc3, 0, 0, 0);
      acc3 = __builtin_amdgcn_mfma_f32_16x16x32_bf16(Ah, Bm, acc3, 0, 0, 0);
      acc3 = __builtin_amdgcn_mfma_f32_16x16x32_bf16(Am, Bh, acc3, 0, 0, 0);
    }
    const float bv3 = b3[wave * 16 + col16];
#pragma unroll
    for (int r = 0; r < 4; ++r) {
      const int row = rbase + r;
      const int col = wave * 16 + col16;   // [0,64)
      wbuf3[(row * 64 + col) ^ ((row & 7) << 2)] = acc3[r] + bv3;
    }
  }
  __syncthreads();

  // ---- row norms: 16 threads/row x 4 cols ----
  if (tid < 256) {
    const int row = tid >> 4, c4 = (tid & 15) * 4;
    const float4 a = *(const float4*)&wbuf3[(row * 64 + c4) ^ ((row & 7) << 2)];
    float s = a.x * a.x + a.y * a.y + a.z * a.z + a.w * a.w;
    s += __shfl_xor(s, 1, 64);
    s += __shfl_xor(s, 2, 64);
    s += __shfl_xor(s, 4, 64);
    s += __shfl_xor(s, 8, 64);
    if ((tid & 15) == 0) nsum[row] = s;
  }
  __syncthreads();
  if (tid < 16) invn[tid] = 1.0f / (sqrtf(nsum[tid]) + EPSF);
  __syncthreads();

  // ---- write out (fp32) ----
  if (tid < 256) {
    const int row = tid >> 4, c4 = (tid & 15) * 4;
    *(float4*)(out + (size_t)(r0 + row) * D_OUT + c4) =
        *(const float4*)&wbuf3[(row * 64 + c4) ^ ((row & 7) << 2)];
  }
  // ---- write normalized split-pack vph/vpm (gram operand) ----
  if (tid < 128) {
    const int lu = tid & 63, ql = tid >> 6;
    const int row = lu & 15, kl = ql * 32 + ((lu >> 4) << 3);
    const float sc = invn[row];
    float4 a, b;
    rd8_swz(wbuf3, 64, row, kl, a, b);
    a.x *= sc; a.y *= sc; a.z *= sc; a.w *= sc;
    b.x *= sc; b.y *= sc; b.z *= sc; b.w *= sc;
    short8 hh, mm;
    splitf8(a, b, hh, mm);
    const size_t off = (((size_t)blockIdx.x * 2 + ql) * 64 + lu) * 8;
    *(short8*)(vph + off) = hh;
    *(short8*)(vpm + off) = mm;
  }
}

// ---------------- full Gram, panel-private LDS accumulation (v9) ----------------
// v9 vs v8 (same math, same edge set, same exact fp32 sums):
//   - 64-row i-panels: LDS 24KB (8K lAh + 16K acc) -> 4 blocks/CU via
//     __launch_bounds__(256,4); grid (128,8)=1024 blocks; 16 waves/CU (2.7x v8).
//   - B-tile software double-buffer: next j-tile's Bh pair loads issue before
//     the current tile's MFMAs -> L2 latency hidden.
//   - diag exclusion hoisted out of the per-pair path: one uniform tile-index
//     compare + precomputed lane-mask (0x1000010000100001<<r) on the ballot.
// Duplicate (i,j)/(j,i) decisions stay bitwise-symmetric: screen MFMA is
// transpose-symmetric; refine cross-terms accumulate separately (g2a/g2b) and
// combine with one commutative add; out-of-band decisions are refine-invariant.
__global__ __launch_bounds__(256, 4)
void gram_lds(const short* __restrict__ vph, const short* __restrict__ vpm,
              const float* __restrict__ out, float* __restrict__ resp) {
  __shared__ __align__(16) short lAh[4 * 1024];   // 8 KB: A-hi, 4 i-tiles
  __shared__ __align__(16) float acc[64 * 64];    // 16 KB res partial
  const int tid = threadIdx.x;
  const int wave = tid >> 6, lane = tid & 63;
  const int I = blockIdx.x;        // i-panel [0,128), 64 rows
  const int sl = blockIdx.y;       // j-slice [0,8), 1024 cols
  const int i0 = I * 64;
  const int jbase = sl * 1024;

  // zero acc (4096 floats = 1024 float4)
#pragma unroll
  for (int u = 0; u < 4; ++u)
    *(float4*)&acc[(u * 256 + tid) * 4] = make_float4(0.f, 0.f, 0.f, 0.f);

  // stage A-hi for the 4 i-tiles (8 KB): 8 wave-uniform 1KB items
  {
    const size_t base = (size_t)I * 4096;
#pragma unroll
    for (int u = 0; u < 2; ++u) {
      const int item = wave * 2 + u;
      __builtin_amdgcn_global_load_lds(
          (const __attribute__((address_space(1))) void*)(vph + base + item * 512 + lane * 8),
          (__attribute__((address_space(3))) void*)(lAh + item * 512), 16, 0, 0);
    }
  }
  __syncthreads();

  // B double-buffer: preload j-tile for u=0
  short8 Bh0, Bh1;
  {
    const short* jb = vph + (size_t)((jbase >> 4) + wave) * 1024;
    Bh0 = *(const short8*)(jb + lane * 8);
    Bh1 = *(const short8*)(jb + 512 + lane * 8);
  }

  for (int u = 0; u < 16; ++u) {
    const int jt = u * 4 + wave;           // this wave's j-tile [0,64)
    const int j0 = jbase + jt * 16;
    // prefetch next iteration's B pair (issues before current MFMAs retire)
    short8 Bn0, Bn1;
    if (u < 15) {
      const short* jn = vph + (size_t)((jbase >> 4) + jt + 4) * 1024;
      Bn0 = *(const short8*)(jn + lane * 8);
      Bn1 = *(const short8*)(jn + 512 + lane * 8);
    }

    f32x4 g[4];
#pragma unroll
    for (int it = 0; it < 4; ++it) g[it] = (f32x4){0.f, 0.f, 0.f, 0.f};
    // hh screen: 8 MFMAs, 4 independent chains; A read from LDS at use
#pragma unroll
    for (int it = 0; it < 4; ++it) {
      const short8 A0 = *(const short8*)(lAh + it * 1024 + lane * 8);
      g[it] = __builtin_amdgcn_mfma_f32_16x16x32_bf16(A0, Bh0, g[it], 0, 0, 0);
    }
#pragma unroll
    for (int it = 0; it < 4; ++it) {
      const short8 A1 = *(const short8*)(lAh + it * 1024 + 512 + lane * 8);
      g[it] = __builtin_amdgcn_mfma_f32_16x16x32_bf16(A1, Bh1, g[it], 0, 0, 0);
    }

    bool band = false;
#pragma unroll
    for (int it = 0; it < 4; ++it)
#pragma unroll
      for (int r = 0; r < 4; ++r) {
        const float f = g[it][r] * g[it][r];
        band = band || (f > BAND_LO && f < BAND_HI);
      }
    if (__any(band)) {
      // refine: cross terms in separate accumulators (bitwise-symmetric)
      const short* jm = vpm + (size_t)((jbase >> 4) + jt) * 1024;
      const short8 Bm0 = *(const short8*)(jm + lane * 8);
      const short8 Bm1 = *(const short8*)(jm + 512 + lane * 8);
      f32x4 g2a[4], g2b[4];
#pragma unroll
      for (int it = 0; it < 4; ++it) {
        g2a[it] = (f32x4){0.f, 0.f, 0.f, 0.f};
        g2b[it] = (f32x4){0.f, 0.f, 0.f, 0.f};
      }
#pragma unroll
      for (int it = 0; it < 4; ++it) {
        const short8 A0 = *(const short8*)(lAh + it * 1024 + lane * 8);
        const short8 A1 = *(const short8*)(lAh + it * 1024 + 512 + lane * 8);
        g2a[it] = __builtin_amdgcn_mfma_f32_16x16x32_bf16(A0, Bm0, g2a[it], 0, 0, 0);
        g2a[it] = __builtin_amdgcn_mfma_f32_16x16x32_bf16(A1, Bm1, g2a[it], 0, 0, 0);
        const size_t abase = (size_t)(I * 4 + it) * 1024;
        const short8 Am0 = *(const short8*)(vpm + abase + lane * 8);
        const short8 Am1 = *(const short8*)(vpm + abase + 512 + lane * 8);
        g2b[it] = __builtin_amdgcn_mfma_f32_16x16x32_bf16(Am0, Bh0, g2b[it], 0, 0, 0);
        g2b[it] = __builtin_amdgcn_mfma_f32_16x16x32_bf16(Am1, Bh1, g2b[it], 0, 0, 0);
      }
#pragma unroll
      for (int it = 0; it < 4; ++it)
#pragma unroll
        for (int r = 0; r < 4; ++r)
          g[it][r] += (g2a[it][r] + g2b[it][r]);   // commutative combine
    }

    // threshold ballot + diag-mask + gather/LDS-accumulate
    const int jtg = (jbase >> 4) + jt;      // global j-tile index
#pragma unroll
    for (int it = 0; it < 4; ++it) {
      const bool diag = (I * 4 + it) == jtg;   // uniform per (it, jt)
#pragma unroll
      for (int r = 0; r < 4; ++r) {
        unsigned long long m = __ballot(g[it][r] * g[it][r] >= THRESH);
        if (diag) m &= ~(0x1000010000100001ull << r);   // drop i==j lanes
        while (m) {   // wave-uniform mask -> uniform control flow
          const int s = __builtin_ctzll(m);
          m &= m - 1;
          const float v = out[(size_t)(j0 + (s & 15)) * D_OUT + lane];
          atomicAdd(&acc[(it * 16 + ((s >> 4) << 2) + r) * 64 + lane], v);
        }
      }
    }
    Bh0 = Bn0;
    Bh1 = Bn1;
  }
  __syncthreads();

  // flush partials: plain coalesced stores, exclusively-owned region
  float* dst = resp + ((size_t)sl * B_ROWS + i0) * D_OUT;
#pragma unroll
  for (int u = 0; u < 4; ++u) {
    const int e = u * 256 + tid;   // float4 index [0,1024)
    *(float4*)&dst[e * 4] = *(const float4*)&acc[e * 4];
  }
}

// ---------------- sum the 8 slice-partials into res ----------------
__global__ __launch_bounds__(256)
void reduce8(const float4* __restrict__ resp, float4* __restrict__ res) {
  const int idx = blockIdx.x * 256 + threadIdx.x;   // [0, 131072)
  float4 a = resp[idx];
#pragma unroll
  for (int s = 1; s < 8; ++s) {
    const float4 b = resp[(size_t)s * (B_ROWS * D_OUT / 4) + idx];
    a.x += b.x; a.y += b.y; a.z += b.z; a.w += b.w;
  }
  res[idx] = a;
}

// ---------------- launch ----------------
#define MB (1024 * 1024)
#define KB 1024

extern "C" void kernel_launch(void* const* d_in, const int* in_sizes, int n_in,
                              void* d_out, int out_size, void* d_ws, size_t ws_size,
                              hipStream_t stream) {
  const float* x  = (const float*)d_in[0];
  const float* W1 = (const float*)d_in[1];
  const float* b1 = (const float*)d_in[2];
  const float* W2 = (const float*)d_in[3];
  const float* b2 = (const float*)d_in[4];
  const float* W3 = (const float*)d_in[5];
  const float* b3 = (const float*)d_in[6];
  float* res = (float*)d_out;

  char* ws = (char*)d_ws;
  float* out = (float*)(ws);                     // 2 MB
  short* vph = (short*)(ws + 2 * MB);            // 1 MB
  short* vpm = (short*)(ws + 3 * MB);            // 1 MB
  short* w1h = (short*)(ws + 4 * MB);            // 256 KB
  short* w1m = (short*)(ws + 4 * MB + 256 * KB);
  short* w2h = (short*)(ws + 4 * MB + 512 * KB);
  short* w2m = (short*)(ws + 4 * MB + 768 * KB);
  short* w3h = (short*)(ws + 5 * MB);            // 32 KB
  short* w3m = (short*)(ws + 5 * MB + 32 * KB);
  float* resp = (float*)(ws + 6 * MB);           // 16 MB partials (8 slices)

  // pack weights to fragment-major bf16 hi/mid (tiny, ~2.2 MB rw)
  wpack<<<136, 256, 0, stream>>>(W1, W2, W3, w1h, w1m, w2h, w2m, w3h, w3m);
  // fused MLP: 512 x 16-row blocks, 2 blocks/CU
  fused_mlp16<<<512, 512, 0, stream>>>(x, w1h, w1m, b1, w2h, w2m, b2,
                                       w3h, w3m, b3, out, vph, vpm);
  // gram v9: 64-row panels, 4 blocks/CU, B double-buffer, hoisted diag mask
  gram_lds<<<dim3(128, 8), 256, 0, stream>>>(vph, vpm, out, resp);
  // sum the 8 slice-partials (overwrites res poison)
  reduce8<<<dim3(B_ROWS * D_OUT / 4 / 256), 256, 0, stream>>>(
      (const float4*)resp, (float4*)res);
}

// Round 10
// 130.560 us; speedup vs baseline: 1.1543x; 1.0183x over previous
//
// v10 resubmit #2 (rounds 8/9 failed at container acquisition, not in the
// kernel: bounds/termination audited clean; source touched only in comments
// to bust any corrupted build cache).
#include <hip/hip_runtime.h>
#include <hip/hip_bf16.h>
#include <math.h>

// Problem dims (fixed by reference)
#define B_ROWS 8192
#define D_IN   256
#define H1_DIM 512
#define H2_DIM 256
#define D_OUT  64
#define EPSF   1e-12f
#define THRESH 0.9f

typedef __attribute__((ext_vector_type(8))) short short8;   // 8 bf16 = 4 VGPR
typedef __attribute__((ext_vector_type(4))) float f32x4;

// fast tanh via hardware exp: tanh(|x|) = (1-e^{-2|x|})/(1+e^{-2|x|}), ~1e-7 rel err
__device__ inline float tanh_fast(float xx) {
  const float ax = fabsf(xx);
  const float t = __expf(-2.0f * ax);
  const float r = (1.0f - t) / (1.0f + t);
  return xx < 0.0f ? -r : r;
}

// split fp32x8 -> bf16 hi + bf16 mid (residual), fragment-packed
__device__ inline void splitf8(float4 a, float4 b, short8& h, short8& m) {
  float v[8] = {a.x, a.y, a.z, a.w, b.x, b.y, b.z, b.w};
  short h8[8], m8[8];
#pragma unroll
  for (int e = 0; e < 8; ++e) {
    __hip_bfloat16 hb = __float2bfloat16(v[e]);
    float hf = __bfloat162float(hb);
    __hip_bfloat16 mb = __float2bfloat16(v[e] - hf);
    h8[e] = *(short*)&hb;
    m8[e] = *(short*)&mb;
  }
  h = *(short8*)h8;
  m = *(short8*)m8;
}

// read 8 logical-consecutive floats at (row, kl) from an XOR-swizzled LDS buf.
// swizzle: dword index ^= (row&7)<<2 (16B-slot spread -> conflict-free b128)
__device__ inline void rd8_swz(const float* buf, int S, int row, int kl,
                               float4& a, float4& b) {
  const int xr = (row & 7) << 2;
  a = *(const float4*)&buf[(row * S + kl) ^ xr];
  b = *(const float4*)&buf[(row * S + kl + 4) ^ xr];
}

// ---------------- weight pre-pack (fragment-major bf16 hi/mid) ----------------
__device__ inline void pack8(const float* __restrict__ src, short* __restrict__ dh,
                             short* __restrict__ dm, int t, int C, int lgq) {
  const int lane = t & 63;
  const int g = t >> 6;
  const int q = g & ((1 << lgq) - 1);
  const int I = g >> lgq;
  const int row = I * 16 + (lane & 15);
  const int k0 = q * 32 + ((lane >> 4) << 3);
  const float* p = src + (size_t)row * C + k0;
  short8 hh, mm;
  splitf8(*(const float4*)p, *(const float4*)(p + 4), hh, mm);
  *(short8*)(dh + (size_t)t * 8) = hh;
  *(short8*)(dm + (size_t)t * 8) = mm;
}

__global__ __launch_bounds__(256)
void wpack(const float* __restrict__ W1, const float* __restrict__ W2,
           const float* __restrict__ W3,
           short* w1h, short* w1m, short* w2h, short* w2m,
           short* w3h, short* w3m) {
  const int b = blockIdx.x, tid = threadIdx.x;
  if (b < 64)        pack8(W1, w1h, w1m, b * 256 + tid, 256, 3);
  else if (b < 128)  pack8(W2, w2h, w2m, (b - 64) * 256 + tid, 512, 4);
  else               pack8(W3, w3h, w3m, (b - 128) * 256 + tid, 256, 3);
}

// ---------------- fully fused MLP, 16-row blocks (round-3 config, unchanged) ----------------
__global__ __launch_bounds__(512, 4)
void fused_mlp16(const float* __restrict__ x,
                 const short* __restrict__ w1h, const short* __restrict__ w1m,
                 const float* __restrict__ b1,
                 const short* __restrict__ w2h, const short* __restrict__ w2m,
                 const float* __restrict__ b2,
                 const short* __restrict__ w3h, const short* __restrict__ w3m,
                 const float* __restrict__ b3,
                 float* __restrict__ out, short* __restrict__ vph,
                 short* __restrict__ vpm) {
  __shared__ __align__(16) char smem[49152];
  short* xph   = (short*)smem;                // 8KB
  short* xpm   = (short*)(smem + 8192);       // 8KB
  float* wbuf1 = (float*)smem;                // 16KB
  float* wbuf3 = (float*)smem;                // 4KB
  short* h1h   = (short*)(smem + 16384);      // 16KB
  short* h1m   = (short*)(smem + 32768);      // 16KB
  float* wbuf2 = (float*)(smem + 16384);      // 16KB
  short* h2ph  = (short*)(smem + 32768);      // 8KB
  short* h2pm  = (short*)(smem + 40960);      // 8KB
  __shared__ float nsum[16];
  __shared__ float invn[16];

  const int tid = threadIdx.x;
  const int wave = tid >> 6, lane = tid & 63;
  const int r0 = blockIdx.x * 16;
  const int col16 = lane & 15;
  const int rbase = (lane >> 4) << 2;   // C-layout row base

  // ---- pack x block (16x256 fp32 -> frag hi/mid): 512 units, 1/thread ----
  {
    const int lu = tid & 63, q = tid >> 6;
    const float* p = x + (size_t)(r0 + (lu & 15)) * D_IN + q * 32 + ((lu >> 4) << 3);
    short8 hh, mm;
    splitf8(*(const float4*)p, *(const float4*)(p + 4), hh, mm);
    const int off = (q * 64 + lu) * 8;
    *(short8*)(xph + off) = hh;
    *(short8*)(xpm + off) = mm;
  }
  __syncthreads();

  // ---- layer1: h1 = tanh(x @ W1^T + b1), N=512; wave owns 4 j-tiles ----
  f32x4 acc1[4];
#pragma unroll
  for (int jj = 0; jj < 4; ++jj) acc1[jj] = (f32x4){0.f, 0.f, 0.f, 0.f};
#pragma unroll 4
  for (int q = 0; q < 8; ++q) {
    const int aoff = (q * 64 + lane) * 8;
    const short8 Ah = *(const short8*)(xph + aoff);
    const short8 Am = *(const short8*)(xpm + aoff);
#pragma unroll
    for (int jj = 0; jj < 4; ++jj) {
      const int boff = (((wave * 4 + jj) * 8 + q) * 64 + lane) * 8;
      const short8 Bh = *(const short8*)(w1h + boff);
      const short8 Bm = *(const short8*)(w1m + boff);
      acc1[jj] = __builtin_amdgcn_mfma_f32_16x16x32_bf16(Ah, Bh, acc1[jj], 0, 0, 0);
      acc1[jj] = __builtin_amdgcn_mfma_f32_16x16x32_bf16(Ah, Bm, acc1[jj], 0, 0, 0);
      acc1[jj] = __builtin_amdgcn_mfma_f32_16x16x32_bf16(Am, Bh, acc1[jj], 0, 0, 0);
    }
  }
  __syncthreads();   // xp dead; [0,16K) becomes wbuf1

  // ---- L1 epilogue: two 256-col halves through swizzled wbuf1 ----
  float bv1[4];
#pragma unroll
  for (int jj = 0; jj < 4; ++jj) bv1[jj] = b1[(wave * 4 + jj) * 16 + col16];
#pragma unroll
  for (int h = 0; h < 2; ++h) {
    if ((wave >> 2) == h) {
#pragma unroll
      for (int jj = 0; jj < 4; ++jj)
#pragma unroll
        for (int r = 0; r < 4; ++r) {
          const int row = rbase + r;
          const int col = ((wave & 3) * 4 + jj) * 16 + col16;   // [0,256)
          wbuf1[(row * 256 + col) ^ ((row & 7) << 2)] = tanh_fast(acc1[jj][r] + bv1[jj]);
        }
    }
    __syncthreads();
    {
      const int lu = tid & 63, ql = tid >> 6;
      const int row = lu & 15, kl = ql * 32 + ((lu >> 4) << 3);
      float4 a, b;
      rd8_swz(wbuf1, 256, row, kl, a, b);
      short8 hh, mm;
      splitf8(a, b, hh, mm);
      const int off = ((h * 8 + ql) * 64 + lu) * 8;
      *(short8*)(h1h + off) = hh;
      *(short8*)(h1m + off) = mm;
    }
    __syncthreads();
  }

  // ---- layer2: h2 = tanh(h1 @ W2^T + b2), N=256; wave owns 2 j-tiles ----
  f32x4 acc2[2];
#pragma unroll
  for (int jj = 0; jj < 2; ++jj) acc2[jj] = (f32x4){0.f, 0.f, 0.f, 0.f};
#pragma unroll 4
  for (int q = 0; q < 16; ++q) {
    const int aoff = (q * 64 + lane) * 8;
    const short8 Ah = *(const short8*)(h1h + aoff);
    const short8 Am = *(const short8*)(h1m + aoff);
#pragma unroll
    for (int jj = 0; jj < 2; ++jj) {
      const int boff = (((wave * 2 + jj) * 16 + q) * 64 + lane) * 8;
      const short8 Bh = *(const short8*)(w2h + boff);
      const short8 Bm = *(const short8*)(w2m + boff);
      acc2[jj] = __builtin_amdgcn_mfma_f32_16x16x32_bf16(Ah, Bh, acc2[jj], 0, 0, 0);
      acc2[jj] = __builtin_amdgcn_mfma_f32_16x16x32_bf16(Ah, Bm, acc2[jj], 0, 0, 0);
      acc2[jj] = __builtin_amdgcn_mfma_f32_16x16x32_bf16(Am, Bh, acc2[jj], 0, 0, 0);
    }
  }
  __syncthreads();   // h1 dead; [16K,32K) becomes wbuf2

  // ---- L2 epilogue ----
  {
    float bv2[2];
#pragma unroll
    for (int jj = 0; jj < 2; ++jj) bv2[jj] = b2[(wave * 2 + jj) * 16 + col16];
#pragma unroll
    for (int jj = 0; jj < 2; ++jj)
#pragma unroll
      for (int r = 0; r < 4; ++r) {
        const int row = rbase + r;
        const int col = (wave * 2 + jj) * 16 + col16;   // [0,256)
        wbuf2[(row * 256 + col) ^ ((row & 7) << 2)] = tanh_fast(acc2[jj][r] + bv2[jj]);
      }
  }
  __syncthreads();
  {
    const int lu = tid & 63, ql = tid >> 6;
    const int row = lu & 15, kl = ql * 32 + ((lu >> 4) << 3);
    float4 a, b;
    rd8_swz(wbuf2, 256, row, kl, a, b);
    short8 hh, mm;
    splitf8(a, b, hh, mm);
    const int off = (ql * 64 + lu) * 8;
    *(short8*)(h2ph + off) = hh;
    *(short8*)(h2pm + off) = mm;
  }
  __syncthreads();

  // ---- layer3: out = h2 @ W3^T + b3, N=64; waves 0-3 ----
  if (wave < 4) {
    f32x4 acc3 = (f32x4){0.f, 0.f, 0.f, 0.f};
#pragma unroll 4
    for (int q = 0; q < 8; ++q) {
      const int aoff = (q * 64 + lane) * 8;
      const short8 Ah = *(const short8*)(h2ph + aoff);
      const short8 Am = *(const short8*)(h2pm + aoff);
      const int boff = ((wave * 8 + q) * 64 + lane) * 8;
      const short8 Bh = *(const short8*)(w3h + boff);
      const short8 Bm = *(const short8*)(w3m + boff);
      acc3 = __builtin_amdgcn_mfma_f32_16x16x32_bf16(Ah, Bh, acc3, 0, 0, 0);
      acc3 = __builtin_amdgcn_mfma_f32_16x16x32_bf16(Ah, Bm, acc3, 0, 0, 0);
      acc3 = __builtin_amdgcn_mfma_f32_16x16x32_bf16(Am, Bh, acc3, 0, 0, 0);
    }
    const float bv3 = b3[wave * 16 + col16];
#pragma unroll
    for (int r = 0; r < 4; ++r) {
      const int row = rbase + r;
      const int col = wave * 16 + col16;   // [0,64)
      wbuf3[(row * 64 + col) ^ ((row & 7) << 2)] = acc3[r] + bv3;
    }
  }
  __syncthreads();

  // ---- row norms: 16 threads/row x 4 cols ----
  if (tid < 256) {
    const int row = tid >> 4, c4 = (tid & 15) * 4;
    const float4 a = *(const float4*)&wbuf3[(row * 64 + c4) ^ ((row & 7) << 2)];
    float s = a.x * a.x + a.y * a.y + a.z * a.z + a.w * a.w;
    s += __shfl_xor(s, 1, 64);
    s += __shfl_xor(s, 2, 64);
    s += __shfl_xor(s, 4, 64);
    s += __shfl_xor(s, 8, 64);
    if ((tid & 15) == 0) nsum[row] = s;
  }
  __syncthreads();
  if (tid < 16) invn[tid] = 1.0f / (sqrtf(nsum[tid]) + EPSF);
  __syncthreads();

  // ---- write out (fp32) ----
  if (tid < 256) {
    const int row = tid >> 4, c4 = (tid & 15) * 4;
    *(float4*)(out + (size_t)(r0 + row) * D_OUT + c4) =
        *(const float4*)&wbuf3[(row * 64 + c4) ^ ((row & 7) << 2)];
  }
  // ---- write normalized split-pack vph/vpm (gram operand) ----
  if (tid < 128) {
    const int lu = tid & 63, ql = tid >> 6;
    const int row = lu & 15, kl = ql * 32 + ((lu >> 4) << 3);
    const float sc = invn[row];
    float4 a, b;
    rd8_swz(wbuf3, 64, row, kl, a, b);
    a.x *= sc; a.y *= sc; a.z *= sc; a.w *= sc;
    b.x *= sc; b.y *= sc; b.z *= sc; b.w *= sc;
    short8 hh, mm;
    splitf8(a, b, hh, mm);
    const size_t off = (((size_t)blockIdx.x * 2 + ql) * 64 + lu) * 8;
    *(short8*)(vph + off) = hh;
    *(short8*)(vpm + off) = mm;
  }
}

// ---------------- full Gram v10: always-3-product, branch-free screen ----------------
// Decision value = 3-product split dot (AhBh+AhBm+AmBh), bitwise-identical to
// all prior verified rounds (AmBm never contributed).  Computed
// unconditionally: no band check, no refine branch (which fired ~65% of
// wave-iterations), no mid-path serialized global loads.  A-panel in 64 VGPRs
// (zero in-loop LDS reads); B straight from L2; LDS = 16KB acc -> 4 blocks/CU.
__global__ __launch_bounds__(256, 4)
void gram3p(const short* __restrict__ vph, const short* __restrict__ vpm,
            const float* __restrict__ out, float* __restrict__ resp) {
  __shared__ __align__(16) float acc[64 * 64];    // 16 KB res partial
  const int tid = threadIdx.x;
  const int wave = tid >> 6, lane = tid & 63;
  const int I = blockIdx.x;        // i-panel [0,128), 64 rows
  const int sl = blockIdx.y;       // j-slice [0,8), 1024 cols
  const int i0 = I * 64;
  const int jbase = sl * 1024;

  // zero acc (4096 floats = 1024 float4)
#pragma unroll
  for (int u = 0; u < 4; ++u)
    *(float4*)&acc[(u * 256 + tid) * 4] = make_float4(0.f, 0.f, 0.f, 0.f);

  // hoist A-panel: 4 i-tiles x 2 ksteps, hi+mid (64 VGPR), straight from L2
  short8 Ah[4][2], Am[4][2];
#pragma unroll
  for (int it = 0; it < 4; ++it) {
    const size_t abase = (size_t)(I * 4 + it) * 1024;
    Ah[it][0] = *(const short8*)(vph + abase + lane * 8);
    Ah[it][1] = *(const short8*)(vph + abase + 512 + lane * 8);
    Am[it][0] = *(const short8*)(vpm + abase + lane * 8);
    Am[it][1] = *(const short8*)(vpm + abase + 512 + lane * 8);
  }
  __syncthreads();   // acc zeroed before any ds_add

  for (int u = 0; u < 16; ++u) {
    const int jt = u * 4 + wave;           // this wave's j-tile [0,64)
    const int j0 = jbase + jt * 16;
    const int jb = (jbase >> 4) + jt;      // global j-tile index
    const short* ph = vph + (size_t)jb * 1024;
    const short* pm = vpm + (size_t)jb * 1024;
    const short8 Bh0 = *(const short8*)(ph + lane * 8);
    const short8 Bh1 = *(const short8*)(ph + 512 + lane * 8);
    const short8 Bm0 = *(const short8*)(pm + lane * 8);
    const short8 Bm1 = *(const short8*)(pm + 512 + lane * 8);

    f32x4 g[4];
#pragma unroll
    for (int it = 0; it < 4; ++it) g[it] = (f32x4){0.f, 0.f, 0.f, 0.f};
    // 6 passes (3 products x 2 ksteps), 4 independent chains, no branches.
#pragma unroll
    for (int it = 0; it < 4; ++it)
      g[it] = __builtin_amdgcn_mfma_f32_16x16x32_bf16(Ah[it][0], Bh0, g[it], 0, 0, 0);
#pragma unroll
    for (int it = 0; it < 4; ++it)
      g[it] = __builtin_amdgcn_mfma_f32_16x16x32_bf16(Ah[it][1], Bh1, g[it], 0, 0, 0);
#pragma unroll
    for (int it = 0; it < 4; ++it)
      g[it] = __builtin_amdgcn_mfma_f32_16x16x32_bf16(Ah[it][0], Bm0, g[it], 0, 0, 0);
#pragma unroll
    for (int it = 0; it < 4; ++it)
      g[it] = __builtin_amdgcn_mfma_f32_16x16x32_bf16(Am[it][0], Bh0, g[it], 0, 0, 0);
#pragma unroll
    for (int it = 0; it < 4; ++it)
      g[it] = __builtin_amdgcn_mfma_f32_16x16x32_bf16(Ah[it][1], Bm1, g[it], 0, 0, 0);
#pragma unroll
    for (int it = 0; it < 4; ++it)
      g[it] = __builtin_amdgcn_mfma_f32_16x16x32_bf16(Am[it][1], Bh1, g[it], 0, 0, 0);

    // threshold ballot + diag-mask + gather/LDS-accumulate
#pragma unroll
    for (int it = 0; it < 4; ++it) {
      const bool diag = (I * 4 + it) == jb;   // uniform per (it, jt)
#pragma unroll
      for (int r = 0; r < 4; ++r) {
        unsigned long long m = __ballot(g[it][r] * g[it][r] >= THRESH);
        if (diag) m &= ~(0x1000010000100001ull << r);   // drop i==j lanes
        while (m) {   // wave-uniform mask -> uniform control flow
          const int s = __builtin_ctzll(m);
          m &= m - 1;
          const float v = out[(size_t)(j0 + (s & 15)) * D_OUT + lane];
          atomicAdd(&acc[(it * 16 + ((s >> 4) << 2) + r) * 64 + lane], v);
        }
      }
    }
  }
  __syncthreads();

  // flush partials: plain coalesced stores, exclusively-owned region
  float* dst = resp + ((size_t)sl * B_ROWS + i0) * D_OUT;
#pragma unroll
  for (int u = 0; u < 4; ++u) {
    const int e = u * 256 + tid;   // float4 index [0,1024)
    *(float4*)&dst[e * 4] = *(const float4*)&acc[e * 4];
  }
}

// ---------------- sum the 8 slice-partials into res ----------------
__global__ __launch_bounds__(256)
void reduce8(const float4* __restrict__ resp, float4* __restrict__ res) {
  const int idx = blockIdx.x * 256 + threadIdx.x;   // [0, 131072)
  float4 a = resp[idx];
#pragma unroll
  for (int s = 1; s < 8; ++s) {
    const float4 b = resp[(size_t)s * (B_ROWS * D_OUT / 4) + idx];
    a.x += b.x; a.y += b.y; a.z += b.z; a.w += b.w;
  }
  res[idx] = a;
}

// ---------------- launch ----------------
#define MB (1024 * 1024)
#define KB 1024

extern "C" void kernel_launch(void* const* d_in, const int* in_sizes, int n_in,
                              void* d_out, int out_size, void* d_ws, size_t ws_size,
                              hipStream_t stream) {
  const float* x  = (const float*)d_in[0];
  const float* W1 = (const float*)d_in[1];
  const float* b1 = (const float*)d_in[2];
  const float* W2 = (const float*)d_in[3];
  const float* b2 = (const float*)d_in[4];
  const float* W3 = (const float*)d_in[5];
  const float* b3 = (const float*)d_in[6];
  float* res = (float*)d_out;

  char* ws = (char*)d_ws;
  float* out = (float*)(ws);                     // 2 MB
  short* vph = (short*)(ws + 2 * MB);            // 1 MB
  short* vpm = (short*)(ws + 3 * MB);            // 1 MB
  short* w1h = (short*)(ws + 4 * MB);            // 256 KB
  short* w1m = (short*)(ws + 4 * MB + 256 * KB);
  short* w2h = (short*)(ws + 4 * MB + 512 * KB);
  short* w2m = (short*)(ws + 4 * MB + 768 * KB);
  short* w3h = (short*)(ws + 5 * MB);            // 32 KB
  short* w3m = (short*)(ws + 5 * MB + 32 * KB);
  float* resp = (float*)(ws + 6 * MB);           // 16 MB partials (8 slices)

  // pack weights to fragment-major bf16 hi/mid (tiny, ~2.2 MB rw)
  wpack<<<136, 256, 0, stream>>>(W1, W2, W3, w1h, w1m, w2h, w2m, w3h, w3m);
  // fused MLP: 512 x 16-row blocks, 2 blocks/CU
  fused_mlp16<<<512, 512, 0, stream>>>(x, w1h, w1m, b1, w2h, w2m, b2,
                                       w3h, w3m, b3, out, vph, vpm);
  // gram v10: branch-free 3-product screen, A in VGPRs, LDS-private accum
  gram3p<<<dim3(128, 8), 256, 0, stream>>>(vph, vpm, out, resp);
  // sum the 8 slice-partials (overwrites res poison)
  reduce8<<<dim3(B_ROWS * D_OUT / 4 / 256), 256, 0, stream>>>(
      (const float4*)resp, (float4*)res);
}

// Round 11
// 114.869 us; speedup vs baseline: 1.3120x; 1.1366x over previous
//
#include <hip/hip_runtime.h>
#include <hip/hip_bf16.h>
#include <math.h>

// Problem dims (fixed by reference)
#define B_ROWS 8192
#define D_IN   256
#define H1_DIM 512
#define H2_DIM 256
#define D_OUT  64
#define EPSF   1e-12f
#define THRESH 0.9f

typedef __attribute__((ext_vector_type(8))) short short8;   // 8 bf16 = 4 VGPR
typedef __attribute__((ext_vector_type(4))) float f32x4;

// fast tanh via hardware exp: tanh(|x|) = (1-e^{-2|x|})/(1+e^{-2|x|}), ~1e-7 rel err
__device__ inline float tanh_fast(float xx) {
  const float ax = fabsf(xx);
  const float t = __expf(-2.0f * ax);
  const float r = (1.0f - t) / (1.0f + t);
  return xx < 0.0f ? -r : r;
}

// split fp32x8 -> bf16 hi + bf16 mid (residual), fragment-packed
__device__ inline void splitf8(float4 a, float4 b, short8& h, short8& m) {
  float v[8] = {a.x, a.y, a.z, a.w, b.x, b.y, b.z, b.w};
  short h8[8], m8[8];
#pragma unroll
  for (int e = 0; e < 8; ++e) {
    __hip_bfloat16 hb = __float2bfloat16(v[e]);
    float hf = __bfloat162float(hb);
    __hip_bfloat16 mb = __float2bfloat16(v[e] - hf);
    h8[e] = *(short*)&hb;
    m8[e] = *(short*)&mb;
  }
  h = *(short8*)h8;
  m = *(short8*)m8;
}

// read 8 logical-consecutive floats at (row, kl) from an XOR-swizzled LDS buf.
// swizzle: dword index ^= (row&7)<<2 (16B-slot spread -> conflict-free b128)
__device__ inline void rd8_swz(const float* buf, int S, int row, int kl,
                               float4& a, float4& b) {
  const int xr = (row & 7) << 2;
  a = *(const float4*)&buf[(row * S + kl) ^ xr];
  b = *(const float4*)&buf[(row * S + kl + 4) ^ xr];
}

// ---------------- weight pre-pack (fragment-major bf16 hi/mid) ----------------
__device__ inline void pack8(const float* __restrict__ src, short* __restrict__ dh,
                             short* __restrict__ dm, int t, int C, int lgq) {
  const int lane = t & 63;
  const int g = t >> 6;
  const int q = g & ((1 << lgq) - 1);
  const int I = g >> lgq;
  const int row = I * 16 + (lane & 15);
  const int k0 = q * 32 + ((lane >> 4) << 3);
  const float* p = src + (size_t)row * C + k0;
  short8 hh, mm;
  splitf8(*(const float4*)p, *(const float4*)(p + 4), hh, mm);
  *(short8*)(dh + (size_t)t * 8) = hh;
  *(short8*)(dm + (size_t)t * 8) = mm;
}

__global__ __launch_bounds__(256)
void wpack(const float* __restrict__ W1, const float* __restrict__ W2,
           const float* __restrict__ W3,
           short* w1h, short* w1m, short* w2h, short* w2m,
           short* w3h, short* w3m) {
  const int b = blockIdx.x, tid = threadIdx.x;
  if (b < 64)        pack8(W1, w1h, w1m, b * 256 + tid, 256, 3);
  else if (b < 128)  pack8(W2, w2h, w2m, (b - 64) * 256 + tid, 512, 4);
  else               pack8(W3, w3h, w3m, (b - 128) * 256 + tid, 256, 3);
}

// ---------------- fully fused MLP, 16-row blocks (R3 config, byte-identical) ----------------
__global__ __launch_bounds__(512, 4)
void fused_mlp16(const float* __restrict__ x,
                 const short* __restrict__ w1h, const short* __restrict__ w1m,
                 const float* __restrict__ b1,
                 const short* __restrict__ w2h, const short* __restrict__ w2m,
                 const float* __restrict__ b2,
                 const short* __restrict__ w3h, const short* __restrict__ w3m,
                 const float* __restrict__ b3,
                 float* __restrict__ out, short* __restrict__ vph,
                 short* __restrict__ vpm, float* __restrict__ res) {
  __shared__ __align__(16) char smem[49152];
  short* xph   = (short*)smem;                // 8KB
  short* xpm   = (short*)(smem + 8192);       // 8KB
  float* wbuf1 = (float*)smem;                // 16KB
  float* wbuf3 = (float*)smem;                // 4KB
  short* h1h   = (short*)(smem + 16384);      // 16KB
  short* h1m   = (short*)(smem + 32768);      // 16KB
  float* wbuf2 = (float*)(smem + 16384);      // 16KB
  short* h2ph  = (short*)(smem + 32768);      // 8KB
  short* h2pm  = (short*)(smem + 40960);      // 8KB
  __shared__ float nsum[16];
  __shared__ float invn[16];

  const int tid = threadIdx.x;
  const int wave = tid >> 6, lane = tid & 63;
  const int r0 = blockIdx.x * 16;
  const int col16 = lane & 15;
  const int rbase = (lane >> 4) << 2;   // C-layout row base

  // zero this block's res rows (harness poisons res): 16*64 = 256 float4
  if (tid < 256) {
    float4* rz = (float4*)(res + (size_t)r0 * D_OUT);
    rz[tid] = make_float4(0.f, 0.f, 0.f, 0.f);
  }

  // ---- pack x block (16x256 fp32 -> frag hi/mid): 512 units, 1/thread ----
  {
    const int lu = tid & 63, q = tid >> 6;
    const float* p = x + (size_t)(r0 + (lu & 15)) * D_IN + q * 32 + ((lu >> 4) << 3);
    short8 hh, mm;
    splitf8(*(const float4*)p, *(const float4*)(p + 4), hh, mm);
    const int off = (q * 64 + lu) * 8;
    *(short8*)(xph + off) = hh;
    *(short8*)(xpm + off) = mm;
  }
  __syncthreads();

  // ---- layer1: h1 = tanh(x @ W1^T + b1), N=512; wave owns 4 j-tiles ----
  f32x4 acc1[4];
#pragma unroll
  for (int jj = 0; jj < 4; ++jj) acc1[jj] = (f32x4){0.f, 0.f, 0.f, 0.f};
#pragma unroll 4
  for (int q = 0; q < 8; ++q) {
    const int aoff = (q * 64 + lane) * 8;
    const short8 Ah = *(const short8*)(xph + aoff);
    const short8 Am = *(const short8*)(xpm + aoff);
#pragma unroll
    for (int jj = 0; jj < 4; ++jj) {
      const int boff = (((wave * 4 + jj) * 8 + q) * 64 + lane) * 8;
      const short8 Bh = *(const short8*)(w1h + boff);
      const short8 Bm = *(const short8*)(w1m + boff);
      acc1[jj] = __builtin_amdgcn_mfma_f32_16x16x32_bf16(Ah, Bh, acc1[jj], 0, 0, 0);
      acc1[jj] = __builtin_amdgcn_mfma_f32_16x16x32_bf16(Ah, Bm, acc1[jj], 0, 0, 0);
      acc1[jj] = __builtin_amdgcn_mfma_f32_16x16x32_bf16(Am, Bh, acc1[jj], 0, 0, 0);
    }
  }
  __syncthreads();   // xp dead; [0,16K) becomes wbuf1

  // ---- L1 epilogue: two 256-col halves through swizzled wbuf1 ----
  float bv1[4];
#pragma unroll
  for (int jj = 0; jj < 4; ++jj) bv1[jj] = b1[(wave * 4 + jj) * 16 + col16];
#pragma unroll
  for (int h = 0; h < 2; ++h) {
    if ((wave >> 2) == h) {
#pragma unroll
      for (int jj = 0; jj < 4; ++jj)
#pragma unroll
        for (int r = 0; r < 4; ++r) {
          const int row = rbase + r;
          const int col = ((wave & 3) * 4 + jj) * 16 + col16;   // [0,256)
          wbuf1[(row * 256 + col) ^ ((row & 7) << 2)] = tanh_fast(acc1[jj][r] + bv1[jj]);
        }
    }
    __syncthreads();
    {
      const int lu = tid & 63, ql = tid >> 6;
      const int row = lu & 15, kl = ql * 32 + ((lu >> 4) << 3);
      float4 a, b;
      rd8_swz(wbuf1, 256, row, kl, a, b);
      short8 hh, mm;
      splitf8(a, b, hh, mm);
      const int off = ((h * 8 + ql) * 64 + lu) * 8;
      *(short8*)(h1h + off) = hh;
      *(short8*)(h1m + off) = mm;
    }
    __syncthreads();
  }

  // ---- layer2: h2 = tanh(h1 @ W2^T + b2), N=256; wave owns 2 j-tiles ----
  f32x4 acc2[2];
#pragma unroll
  for (int jj = 0; jj < 2; ++jj) acc2[jj] = (f32x4){0.f, 0.f, 0.f, 0.f};
#pragma unroll 4
  for (int q = 0; q < 16; ++q) {
    const int aoff = (q * 64 + lane) * 8;
    const short8 Ah = *(const short8*)(h1h + aoff);
    const short8 Am = *(const short8*)(h1m + aoff);
#pragma unroll
    for (int jj = 0; jj < 2; ++jj) {
      const int boff = (((wave * 2 + jj) * 16 + q) * 64 + lane) * 8;
      const short8 Bh = *(const short8*)(w2h + boff);
      const short8 Bm = *(const short8*)(w2m + boff);
      acc2[jj] = __builtin_amdgcn_mfma_f32_16x16x32_bf16(Ah, Bh, acc2[jj], 0, 0, 0);
      acc2[jj] = __builtin_amdgcn_mfma_f32_16x16x32_bf16(Ah, Bm, acc2[jj], 0, 0, 0);
      acc2[jj] = __builtin_amdgcn_mfma_f32_16x16x32_bf16(Am, Bh, acc2[jj], 0, 0, 0);
    }
  }
  __syncthreads();   // h1 dead; [16K,32K) becomes wbuf2

  // ---- L2 epilogue ----
  {
    float bv2[2];
#pragma unroll
    for (int jj = 0; jj < 2; ++jj) bv2[jj] = b2[(wave * 2 + jj) * 16 + col16];
#pragma unroll
    for (int jj = 0; jj < 2; ++jj)
#pragma unroll
      for (int r = 0; r < 4; ++r) {
        const int row = rbase + r;
        const int col = (wave * 2 + jj) * 16 + col16;   // [0,256)
        wbuf2[(row * 256 + col) ^ ((row & 7) << 2)] = tanh_fast(acc2[jj][r] + bv2[jj]);
      }
  }
  __syncthreads();
  {
    const int lu = tid & 63, ql = tid >> 6;
    const int row = lu & 15, kl = ql * 32 + ((lu >> 4) << 3);
    float4 a, b;
    rd8_swz(wbuf2, 256, row, kl, a, b);
    short8 hh, mm;
    splitf8(a, b, hh, mm);
    const int off = (ql * 64 + lu) * 8;
    *(short8*)(h2ph + off) = hh;
    *(short8*)(h2pm + off) = mm;
  }
  __syncthreads();

  // ---- layer3: out = h2 @ W3^T + b3, N=64; waves 0-3 ----
  if (wave < 4) {
    f32x4 acc3 = (f32x4){0.f, 0.f, 0.f, 0.f};
#pragma unroll 4
    for (int q = 0; q < 8; ++q) {
      const int aoff = (q * 64 + lane) * 8;
      const short8 Ah = *(const short8*)(h2ph + aoff);
      const short8 Am = *(const short8*)(h2pm + aoff);
      const int boff = ((wave * 8 + q) * 64 + lane) * 8;
      const short8 Bh = *(const short8*)(w3h + boff);
      const short8 Bm = *(const short8*)(w3m + boff);
      acc3 = __builtin_amdgcn_mfma_f32_16x16x32_bf16(Ah, Bh, acc3, 0, 0, 0);
      acc3 = __builtin_amdgcn_mfma_f32_16x16x32_bf16(Ah, Bm, acc3, 0, 0, 0);
      acc3 = __builtin_amdgcn_mfma_f32_16x16x32_bf16(Am, Bh, acc3, 0, 0, 0);
    }
    const float bv3 = b3[wave * 16 + col16];
#pragma unroll
    for (int r = 0; r < 4; ++r) {
      const int row = rbase + r;
      const int col = wave * 16 + col16;   // [0,64)
      wbuf3[(row * 64 + col) ^ ((row & 7) << 2)] = acc3[r] + bv3;
    }
  }
  __syncthreads();

  // ---- row norms: 16 threads/row x 4 cols ----
  if (tid < 256) {
    const int row = tid >> 4, c4 = (tid & 15) * 4;
    const float4 a = *(const float4*)&wbuf3[(row * 64 + c4) ^ ((row & 7) << 2)];
    float s = a.x * a.x + a.y * a.y + a.z * a.z + a.w * a.w;
    s += __shfl_xor(s, 1, 64);
    s += __shfl_xor(s, 2, 64);
    s += __shfl_xor(s, 4, 64);
    s += __shfl_xor(s, 8, 64);
    if ((tid & 15) == 0) nsum[row] = s;
  }
  __syncthreads();
  if (tid < 16) invn[tid] = 1.0f / (sqrtf(nsum[tid]) + EPSF);
  __syncthreads();

  // ---- write out (fp32) ----
  if (tid < 256) {
    const int row = tid >> 4, c4 = (tid & 15) * 4;
    *(float4*)(out + (size_t)(r0 + row) * D_OUT + c4) =
        *(const float4*)&wbuf3[(row * 64 + c4) ^ ((row & 7) << 2)];
  }
  // ---- write normalized split-pack vph/vpm (gram operand) ----
  if (tid < 128) {
    const int lu = tid & 63, ql = tid >> 6;
    const int row = lu & 15, kl = ql * 32 + ((lu >> 4) << 3);
    const float sc = invn[row];
    float4 a, b;
    rd8_swz(wbuf3, 64, row, kl, a, b);
    a.x *= sc; a.y *= sc; a.z *= sc; a.w *= sc;
    b.x *= sc; b.y *= sc; b.z *= sc; b.w *= sc;
    short8 hh, mm;
    splitf8(a, b, hh, mm);
    const size_t off = (((size_t)blockIdx.x * 2 + ql) * 64 + lu) * 8;
    *(short8*)(vph + off) = hh;
    *(short8*)(vpm + off) = mm;
  }
}

// ---------------- triangular Gram v11: always-3-product, branch-free ----------------
// res[i] = sum_{j != i, fid >= 0.9} out[j]
// Base = R3's v5 (best-measured structure: triangular 2080 blocks, ballot +
// wave-cooperative mirrored global-atomic scatter).  v11 changes ONLY the
// value computation: the 3-product split dot (AhBh+AhBm+AmBh) is computed
// UNCONDITIONALLY in v5's exact pass order.  At triangular density v5's
// "rare" refine fired ~87% of tt-iters (P(any band in 2048 pairs)), with 16
// serialized per-tile A-mid global loads each — v11 deletes the branch and
// stages A-mid once into LDS (32KB total, v4's footprint).
// Edge set identical to v5: banded pairs get bitwise-same g (same pass
// order); out-of-band pairs decide identically by the +-0.008 screen bound.
__global__ __launch_bounds__(256, 2)
void gram_accum(const short* __restrict__ vph, const short* __restrict__ vpm,
                const float* __restrict__ out, float* __restrict__ res) {
  __shared__ __align__(16) short lAh[8 * 1024];   // 16 KB: A hi, 8 i-tiles
  __shared__ __align__(16) short lAm[8 * 1024];   // 16 KB: A mid
  const int tid = threadIdx.x;
  const int wave = tid >> 6, lane = tid & 63;

  // triangular decode: block t -> (I, Jc) with 0 <= I <= Jc < 64
  const int t = blockIdx.x;
  int I = (int)((129.0f - sqrtf(16641.0f - 8.0f * (float)t)) * 0.5f);
  if (I < 0) I = 0;
  while (64 * (I + 1) - ((I + 1) * I) / 2 <= t) ++I;
  while (64 * I - (I * (I - 1)) / 2 > t) --I;
  const int Jc = I + (t - (64 * I - (I * (I - 1)) / 2));
  const int i0 = I * 128;    // 8 i-tiles
  const int j0c = Jc * 128;  // 8 j-tiles

  // stage A hi+mid for the 8 i-tiles (32 KB): 32 wave-uniform 1KB items
  {
    const size_t base = (size_t)I * 8192;
#pragma unroll
    for (int u = 0; u < 8; ++u) {
      const int item = wave * 8 + u;
      const short* src;
      short* dst;
      if (item < 16) { src = vph + base + item * 512; dst = lAh + item * 512; }
      else           { src = vpm + base + (item - 16) * 512; dst = lAm + (item - 16) * 512; }
      __builtin_amdgcn_global_load_lds(
          (const __attribute__((address_space(1))) void*)(src + lane * 8),
          (__attribute__((address_space(3))) void*)dst, 16, 0, 0);
    }
  }
  __syncthreads();

#pragma unroll
  for (int tt = 0; tt < 2; ++tt) {
    const int jt = wave * 2 + tt;
    const int j0 = j0c + jt * 16;
    const short* jb_h = vph + (size_t)(j0 >> 4) * 1024;
    const short* jb_m = vpm + (size_t)(j0 >> 4) * 1024;
    short8 Bh0 = *(const short8*)(jb_h + lane * 8);
    short8 Bh1 = *(const short8*)(jb_h + 512 + lane * 8);
    short8 Bm0 = *(const short8*)(jb_m + lane * 8);
    short8 Bm1 = *(const short8*)(jb_m + 512 + lane * 8);

    f32x4 g[8];
#pragma unroll
    for (int it = 0; it < 8; ++it) g[it] = (f32x4){0.f, 0.f, 0.f, 0.f};
    // v5 pass order: Ah0Bh0, Ah1Bh1 (screen) then Ah0Bm0, Ah1Bm1, Am0Bh0,
    // Am1Bh1 (refine) — now unconditional; 8 independent chains per pass.
#pragma unroll
    for (int it = 0; it < 8; ++it) {
      const short8 A0 = *(const short8*)(lAh + it * 1024 + lane * 8);
      g[it] = __builtin_amdgcn_mfma_f32_16x16x32_bf16(A0, Bh0, g[it], 0, 0, 0);
    }
#pragma unroll
    for (int it = 0; it < 8; ++it) {
      const short8 A1 = *(const short8*)(lAh + it * 1024 + 512 + lane * 8);
      g[it] = __builtin_amdgcn_mfma_f32_16x16x32_bf16(A1, Bh1, g[it], 0, 0, 0);
    }
#pragma unroll
    for (int it = 0; it < 8; ++it) {
      const short8 A0 = *(const short8*)(lAh + it * 1024 + lane * 8);
      g[it] = __builtin_amdgcn_mfma_f32_16x16x32_bf16(A0, Bm0, g[it], 0, 0, 0);
    }
#pragma unroll
    for (int it = 0; it < 8; ++it) {
      const short8 A1 = *(const short8*)(lAh + it * 1024 + 512 + lane * 8);
      g[it] = __builtin_amdgcn_mfma_f32_16x16x32_bf16(A1, Bm1, g[it], 0, 0, 0);
    }
#pragma unroll
    for (int it = 0; it < 8; ++it) {
      const short8 M0 = *(const short8*)(lAm + it * 1024 + lane * 8);
      g[it] = __builtin_amdgcn_mfma_f32_16x16x32_bf16(M0, Bh0, g[it], 0, 0, 0);
    }
#pragma unroll
    for (int it = 0; it < 8; ++it) {
      const short8 M1 = *(const short8*)(lAm + it * 1024 + 512 + lane * 8);
      g[it] = __builtin_amdgcn_mfma_f32_16x16x32_bf16(M1, Bh1, g[it], 0, 0, 0);
    }

    // ballot + wave-cooperative mirrored scatter (i < j only), as v5
    const int jl = j0 + (lane & 15);
#pragma unroll
    for (int it = 0; it < 8; ++it)
#pragma unroll
      for (int r = 0; r < 4; ++r) {
        const int il = i0 + it * 16 + (lane >> 4) * 4 + r;
        unsigned long long m =
            __ballot((g[it][r] * g[it][r] >= THRESH) && (il != jl));
        while (m) {
          const int s = __builtin_ctzll(m);
          m &= m - 1;
          const int js = j0 + (s & 15);
          const int is = i0 + it * 16 + ((s >> 4) << 2) + r;
          if (is < js) {
            atomicAdd(res + (size_t)is * D_OUT + lane, out[(size_t)js * D_OUT + lane]);
            atomicAdd(res + (size_t)js * D_OUT + lane, out[(size_t)is * D_OUT + lane]);
          }
        }
      }
  }
}

// ---------------- launch ----------------
#define MB (1024 * 1024)
#define KB 1024

extern "C" void kernel_launch(void* const* d_in, const int* in_sizes, int n_in,
                              void* d_out, int out_size, void* d_ws, size_t ws_size,
                              hipStream_t stream) {
  const float* x  = (const float*)d_in[0];
  const float* W1 = (const float*)d_in[1];
  const float* b1 = (const float*)d_in[2];
  const float* W2 = (const float*)d_in[3];
  const float* b2 = (const float*)d_in[4];
  const float* W3 = (const float*)d_in[5];
  const float* b3 = (const float*)d_in[6];
  float* res = (float*)d_out;

  char* ws = (char*)d_ws;
  float* out = (float*)(ws);                     // 2 MB
  short* vph = (short*)(ws + 2 * MB);            // 1 MB
  short* vpm = (short*)(ws + 3 * MB);            // 1 MB
  short* w1h = (short*)(ws + 4 * MB);            // 256 KB
  short* w1m = (short*)(ws + 4 * MB + 256 * KB);
  short* w2h = (short*)(ws + 4 * MB + 512 * KB);
  short* w2m = (short*)(ws + 4 * MB + 768 * KB);
  short* w3h = (short*)(ws + 5 * MB);            // 32 KB
  short* w3m = (short*)(ws + 5 * MB + 32 * KB);

  // pack weights to fragment-major bf16 hi/mid (tiny, ~2.2 MB rw)
  wpack<<<136, 256, 0, stream>>>(W1, W2, W3, w1h, w1m, w2h, w2m, w3h, w3m);
  // fused MLP: 512 x 16-row blocks, 2 blocks/CU (R3 config, zeroes res)
  fused_mlp16<<<512, 512, 0, stream>>>(x, w1h, w1m, b1, w2h, w2m, b2,
                                       w3h, w3m, b3, out, vph, vpm, res);
  // gram v11: triangular superblocks, always-3-product, mirrored scatter
  gram_accum<<<dim3(2080), 256, 0, stream>>>(vph, vpm, out, res);
}